// Round 7
// baseline (652.535 us; speedup 1.0000x reference)
//
#include <hip/hip_runtime.h>
#include <hip/hip_bf16.h>

#define DD 128

typedef short bf16x8 __attribute__((ext_vector_type(8)));
typedef short bf16x4 __attribute__((ext_vector_type(4)));
typedef float f32x4 __attribute__((ext_vector_type(4)));

__device__ __forceinline__ unsigned short f2b(float f) {
  unsigned int u = __float_as_uint(f);
  u = u + 0x7FFFu + ((u >> 16) & 1u);
  return (unsigned short)(u >> 16);
}
__device__ __forceinline__ float b2f(unsigned short u) {
  return __uint_as_float((unsigned int)u << 16);
}

// ---------------- per-node in-degree ----------------
__global__ void count_kernel(const int* __restrict__ ei, int* __restrict__ cnt, int E) {
  int i = blockIdx.x * blockDim.x + threadIdx.x;
  if (i < E) atomicAdd(&cnt[ei[E + i]], 1);
}

// ---------------- prefix scan (3 kernels) ----------------
__global__ __launch_bounds__(256) void scan_a(const int* __restrict__ cnt,
                                              int* __restrict__ off,
                                              int* __restrict__ bsum, int N) {
  __shared__ int wsum[4];
  const int t = threadIdx.x;
  const int i0 = blockIdx.x * 1024 + t * 4;
  int4 v = {0, 0, 0, 0};
  if (i0 + 3 < N) v = *reinterpret_cast<const int4*>(cnt + i0);
  else {
    if (i0 < N)     v.x = cnt[i0];
    if (i0 + 1 < N) v.y = cnt[i0 + 1];
    if (i0 + 2 < N) v.z = cnt[i0 + 2];
    if (i0 + 3 < N) v.w = cnt[i0 + 3];
  }
  const int s1 = v.x, s2 = s1 + v.y, s3 = s2 + v.z, tot = s3 + v.w;
  const int lane = t & 63, wv = t >> 6;
  int sc = tot;
#pragma unroll
  for (int d = 1; d < 64; d <<= 1) {
    int u = __shfl_up(sc, d);
    if (lane >= d) sc += u;
  }
  if (lane == 63) wsum[wv] = sc;
  __syncthreads();
  int wpre = 0;
  for (int w = 0; w < wv; ++w) wpre += wsum[w];
  const int excl = wpre + sc - tot;
  if (i0 < N)     off[i0]     = excl;
  if (i0 + 1 < N) off[i0 + 1] = excl + s1;
  if (i0 + 2 < N) off[i0 + 2] = excl + s2;
  if (i0 + 3 < N) off[i0 + 3] = excl + s3;
  if (t == 255) bsum[blockIdx.x] = wpre + sc;
}

__global__ void scan_b(int* __restrict__ bsum, int B) {
  const int t = threadIdx.x;
  const int v0 = (t < B) ? bsum[t] : 0;
  int v = v0;
#pragma unroll
  for (int d = 1; d < 64; d <<= 1) {
    int u = __shfl_up(v, d);
    if (t >= d) v += u;
  }
  if (t < B) bsum[t] = v - v0;
}

__global__ __launch_bounds__(256) void scan_c(int* __restrict__ off, int* __restrict__ cur,
                                              const int* __restrict__ bsum, int N, int E) {
  const int t = threadIdx.x;
  const int add = bsum[blockIdx.x];
  const int i0 = blockIdx.x * 1024 + t * 4;
#pragma unroll
  for (int k = 0; k < 4; ++k) {
    const int i = i0 + k;
    if (i < N) {
      const int o = off[i] + add;
      off[i] = o;
      cur[i] = o;
    }
  }
  if (blockIdx.x == 0 && t == 0) off[N] = E;
}

__global__ void fill_kernel(const int* __restrict__ ei, int* __restrict__ cur,
                            int* __restrict__ perm, int E) {
  int i = blockIdx.x * blockDim.x + threadIdx.x;
  if (i < E) {
    const int d = ei[E + i];
    const int pos = atomicAdd(&cur[d], 1);
    perm[pos] = i;
  }
}

// ---------------- PQ precompute: PQ = x @ [W_a | W_b]  (bf16 out) ----------------
__global__ __launch_bounds__(256, 2) void pq_kernel(
    const float* __restrict__ x,
    const float* __restrict__ We1,
    unsigned short* __restrict__ pq,
    int N)
{
  __shared__ __align__(16) unsigned short x_lds[64][128];

  const int tid  = threadIdx.x;
  const int wv   = tid >> 6;
  const int lane = tid & 63;
  const int lg   = lane >> 4;
  const int lm   = lane & 15;

  bf16x8 wf[4][4];
#pragma unroll
  for (int nf = 0; nf < 4; ++nf) {
    const int n    = wv * 64 + nf * 16 + lm;
    const int col  = n & 127;
    const int kro  = (n >> 7) * 128;
#pragma unroll
    for (int kb = 0; kb < 4; ++kb) {
      bf16x8 f;
#pragma unroll
      for (int j = 0; j < 8; ++j)
        f[j] = (short)f2b(We1[(kro + kb * 32 + lg * 8 + j) * DD + col]);
      wf[kb][nf] = f;
    }
  }

  const int nbase = blockIdx.x * 64;

#pragma unroll
  for (int it = 0; it < 4; ++it) {
    const int q = tid + it * 256;
    const int r = q >> 4;
    const int c = q & 15;
    int gr = nbase + r; if (gr >= N) gr = N - 1;
    const float* p = x + (size_t)gr * DD + c * 8;
    const float4 va = *reinterpret_cast<const float4*>(p);
    const float4 vb = *reinterpret_cast<const float4*>(p + 4);
    bf16x8 o;
    o[0] = (short)f2b(va.x); o[1] = (short)f2b(va.y);
    o[2] = (short)f2b(va.z); o[3] = (short)f2b(va.w);
    o[4] = (short)f2b(vb.x); o[5] = (short)f2b(vb.y);
    o[6] = (short)f2b(vb.z); o[7] = (short)f2b(vb.w);
    *reinterpret_cast<bf16x8*>(&x_lds[r][(c ^ (r & 7)) * 8]) = o;
  }
  __syncthreads();

  f32x4 acc[4][4];
#pragma unroll
  for (int mf = 0; mf < 4; ++mf)
#pragma unroll
    for (int nf = 0; nf < 4; ++nf)
      acc[mf][nf] = (f32x4){0.f, 0.f, 0.f, 0.f};

#pragma unroll
  for (int kb = 0; kb < 4; ++kb) {
    bf16x8 a[4];
#pragma unroll
    for (int mf = 0; mf < 4; ++mf) {
      const int r = mf * 16 + lm;
      a[mf] = *reinterpret_cast<const bf16x8*>(&x_lds[r][((kb * 4 + lg) ^ (r & 7)) * 8]);
    }
#pragma unroll
    for (int mf = 0; mf < 4; ++mf)
#pragma unroll
      for (int nf = 0; nf < 4; ++nf)
        acc[mf][nf] = __builtin_amdgcn_mfma_f32_16x16x32_bf16(a[mf], wf[kb][nf], acc[mf][nf], 0, 0, 0);
  }

#pragma unroll
  for (int mf = 0; mf < 4; ++mf)
#pragma unroll
    for (int rg = 0; rg < 4; ++rg) {
      const int gm = nbase + mf * 16 + lg * 4 + rg;
      if (gm < N) {
#pragma unroll
        for (int nf = 0; nf < 4; ++nf)
          pq[(size_t)gm * 256 + wv * 64 + nf * 16 + lm] = f2b(acc[mf][nf][rg]);
      }
    }
}

// ---------------- edge MLP: barrier-free, wave-independent, weights in LDS ----
// Each wave owns 16 edges per unit; E % 16 == 0 (600000). No __syncthreads in loop.
__global__ __launch_bounds__(256, 2) void edge_mlp_kernel(
    const unsigned short* __restrict__ pq,   // [N][256] bf16: [P|Q]
    const int* __restrict__ ei,              // [2][E]
    const float* __restrict__ ea,            // [E][128] f32
    const float* __restrict__ We1,           // rows 256..383 = W_c
    const float* __restrict__ be1,
    const float* __restrict__ We2,
    const float* __restrict__ be2,
    float* __restrict__ e_out,               // [E][128] f32
    int E)
{
  // w1T/w2T: [n][k] bf16, chunk-swizzled (chunk j of row n at j^(n&7)).
  __shared__ __align__(16) unsigned short w1T[128 * 128];
  __shared__ __align__(16) unsigned short w2T[128 * 128];
  __shared__ __align__(16) unsigned short h_lds[4][16 * 128];  // per-wave h slice

  const int tid  = threadIdx.x;
  const int wv   = tid >> 6;
  const int lane = tid & 63;
  const int lg   = lane >> 4;
  const int lm   = lane & 15;
  const int swz  = lm & 7;

  // ---- stage transposed+swizzled weights (once per block) ----
  {
    const int n  = tid & 127;
    const int k0 = (tid >> 7) * 64;
    for (int p = 0; p < 32; ++p) {
      const int k = k0 + 2 * p;
      const unsigned int w1p = (unsigned int)f2b(We1[(256 + k) * DD + n]) |
                               ((unsigned int)f2b(We1[(257 + k) * DD + n]) << 16);
      const unsigned int w2p = (unsigned int)f2b(We2[k * DD + n]) |
                               ((unsigned int)f2b(We2[(k + 1) * DD + n]) << 16);
      const int idx = n * 128 + (((k >> 3) ^ (n & 7)) << 3) + (k & 7);
      *reinterpret_cast<unsigned int*>(&w1T[idx]) = w1p;
      *reinterpret_cast<unsigned int*>(&w2T[idx]) = w2p;
    }
  }

  // ---- biases (resident) ----
  float4 b1v[8];   // b1 for n = nf*16 + 4lg + rg   (L1 output row dim)
  float  b2s[8];   // b2 for n = nf*16 + lm          (L2 output col dim)
#pragma unroll
  for (int nf = 0; nf < 8; ++nf) {
    b1v[nf] = *reinterpret_cast<const float4*>(&be1[nf * 16 + 4 * lg]);
    b2s[nf] = be2[nf * 16 + lm];
  }
  __syncthreads();  // weights visible; ONLY barrier in the kernel

  unsigned short* hw = &h_lds[wv][0];

  const int nunits  = E >> 4;          // 37500
  const int ustride = gridDim.x << 2;

  for (int u = (blockIdx.x << 2) + wv; u < nunits; u += ustride) {
    const int ebase = u << 4;
    const int erow  = ebase + lm;      // this lane's edge for loads
    const int se = ei[erow];
    const int de = ei[E + erow];

    // ---- ea -> bf16 B-fragments (col = edge = lm, k = kb*32 + lg*8 + j) ----
    bf16x8 eaf[4];
    const float* er = ea + (size_t)erow * DD;
#pragma unroll
    for (int kb = 0; kb < 4; ++kb) {
      const float4 va = *reinterpret_cast<const float4*>(er + kb * 32 + lg * 8);
      const float4 vb = *reinterpret_cast<const float4*>(er + kb * 32 + lg * 8 + 4);
      bf16x8 o;
      o[0] = (short)f2b(va.x); o[1] = (short)f2b(va.y);
      o[2] = (short)f2b(va.z); o[3] = (short)f2b(va.w);
      o[4] = (short)f2b(vb.x); o[5] = (short)f2b(vb.y);
      o[6] = (short)f2b(vb.z); o[7] = (short)f2b(vb.w);
      eaf[kb] = o;
    }

    // ---- acc init = P[src] + Q[dest] + b1  (lane holds n = nf*16+4lg+rg, edge=lm) ----
    f32x4 acc[8];
    const unsigned short* pr = pq + (size_t)se * 256;
    const unsigned short* qr = pq + (size_t)de * 256 + 128;
#pragma unroll
    for (int nf = 0; nf < 8; ++nf) {
      const ushort4 pv = *reinterpret_cast<const ushort4*>(pr + nf * 16 + 4 * lg);
      const ushort4 qv = *reinterpret_cast<const ushort4*>(qr + nf * 16 + 4 * lg);
      acc[nf][0] = b2f(pv.x) + b2f(qv.x) + b1v[nf].x;
      acc[nf][1] = b2f(pv.y) + b2f(qv.y) + b1v[nf].y;
      acc[nf][2] = b2f(pv.z) + b2f(qv.z) + b1v[nf].z;
      acc[nf][3] = b2f(pv.w) + b2f(qv.w) + b1v[nf].w;
    }

    // ---- L1 (swapped): acc[nf] += W_c[n-block nf] x ea ----
#pragma unroll
    for (int kb = 0; kb < 4; ++kb) {
#pragma unroll
      for (int nf = 0; nf < 8; ++nf) {
        const bf16x8 wf = *reinterpret_cast<const bf16x8*>(
            &w1T[(nf * 16 + lm) * 128 + (((kb * 4 + lg) ^ swz) << 3)]);
        acc[nf] = __builtin_amdgcn_mfma_f32_16x16x32_bf16(wf, eaf[kb], acc[nf], 0, 0, 0);
      }
    }

    // ---- h = relu(acc) -> per-wave LDS  h[edge=lm][n = nf*16+4lg+rg] ----
#pragma unroll
    for (int nf = 0; nf < 8; ++nf) {
      bf16x4 hv;
#pragma unroll
      for (int rg = 0; rg < 4; ++rg) {
        const float v = acc[nf][rg];
        hv[rg] = (short)f2b(v > 0.f ? v : 0.f);
      }
      const int c8 = 2 * nf + (lg >> 1);
      *reinterpret_cast<bf16x4*>(&hw[lm * 128 + ((c8 ^ swz) << 3) + 4 * (lg & 1)]) = hv;
    }

    // ---- L2 A-fragments from h (row = edge = lm, k = kb*32 + lg*8) ----
    bf16x8 hf[4];
#pragma unroll
    for (int kb = 0; kb < 4; ++kb)
      hf[kb] = *reinterpret_cast<const bf16x8*>(
          &hw[lm * 128 + (((kb * 4 + lg) ^ swz) << 3)]);

    // ---- L2 (non-swapped): out[edge = 4lg+rg][n = nf*16+lm]; bias in C-init ----
    f32x4 acc2[8];
#pragma unroll
    for (int nf = 0; nf < 8; ++nf)
      acc2[nf] = (f32x4){b2s[nf], b2s[nf], b2s[nf], b2s[nf]};

#pragma unroll
    for (int kb = 0; kb < 4; ++kb) {
#pragma unroll
      for (int nf = 0; nf < 8; ++nf) {
        const bf16x8 wf = *reinterpret_cast<const bf16x8*>(
            &w2T[(nf * 16 + lm) * 128 + (((kb * 4 + lg) ^ swz) << 3)]);
        acc2[nf] = __builtin_amdgcn_mfma_f32_16x16x32_bf16(hf[kb], wf, acc2[nf], 0, 0, 0);
      }
    }

    // ---- store: 4 rows x 64B contiguous per instruction (r5-proven pattern) ----
    float* eo = e_out + (size_t)(ebase + 4 * lg) * DD + lm;
#pragma unroll
    for (int rg = 0; rg < 4; ++rg)
#pragma unroll
      for (int nf = 0; nf < 8; ++nf)
        eo[(size_t)rg * DD + nf * 16] = acc2[nf][rg];
  }
}

// ---------------- CSR scatter-mean: wave per node, 4-deep unroll ----------------
__global__ __launch_bounds__(256) void agg_kernel(const float* __restrict__ e_out,
                                                  const int* __restrict__ off,
                                                  const int* __restrict__ perm,
                                                  float* __restrict__ agg, int N) {
  const int wv   = threadIdx.x >> 6;
  const int lane = threadIdx.x & 63;
  const int nid  = blockIdx.x * 4 + wv;
  if (nid >= N) return;
  const int o0 = off[nid], o1 = off[nid + 1];
  float2 s0 = {0.f, 0.f}, s1 = {0.f, 0.f}, s2 = {0.f, 0.f}, s3 = {0.f, 0.f};
  int j = o0;
  for (; j + 4 <= o1; j += 4) {
    const int r0 = perm[j], r1 = perm[j + 1], r2 = perm[j + 2], r3 = perm[j + 3];
    const float2 v0 = *reinterpret_cast<const float2*>(e_out + (size_t)r0 * DD + (lane << 1));
    const float2 v1 = *reinterpret_cast<const float2*>(e_out + (size_t)r1 * DD + (lane << 1));
    const float2 v2 = *reinterpret_cast<const float2*>(e_out + (size_t)r2 * DD + (lane << 1));
    const float2 v3 = *reinterpret_cast<const float2*>(e_out + (size_t)r3 * DD + (lane << 1));
    s0.x += v0.x; s0.y += v0.y;
    s1.x += v1.x; s1.y += v1.y;
    s2.x += v2.x; s2.y += v2.y;
    s3.x += v3.x; s3.y += v3.y;
  }
  for (; j < o1; ++j) {
    const int r = perm[j];
    const float2 v = *reinterpret_cast<const float2*>(e_out + (size_t)r * DD + (lane << 1));
    s0.x += v.x; s0.y += v.y;
  }
  const int deg = o1 - o0;
  const float inv = deg > 0 ? 1.f / (float)deg : 0.f;
  float2 o;
  o.x = (s0.x + s1.x + s2.x + s3.x) * inv;
  o.y = (s0.y + s1.y + s2.y + s3.y) * inv;
  *reinterpret_cast<float2*>(agg + (size_t)nid * DD + (lane << 1)) = o;
}

// ---------------- node MLP ----------------
__global__ __launch_bounds__(256, 2) void node_mlp_kernel(
    const float* __restrict__ x,
    const float* __restrict__ Wn1,
    const float* __restrict__ bn1,
    const float* __restrict__ Wn2,
    const float* __restrict__ bn2,
    float* __restrict__ xout,        // in: agg mean, out: x_out
    int N)
{
  __shared__ __align__(16) unsigned short A_lds[64][264];
  __shared__ __align__(16) unsigned short h_lds[64][136];

  const int tid  = threadIdx.x;
  const int wv   = tid >> 6;
  const int lane = tid & 63;
  const int lg   = lane >> 4;
  const int lm   = lane & 15;

  bf16x8 w1f[8][2];
  bf16x8 w2f[4][2];
  float b1[2], b2[2];
#pragma unroll
  for (int nf = 0; nf < 2; ++nf) {
    const int n = wv * 32 + nf * 16 + lm;
    b1[nf] = bn1[n];
    b2[nf] = bn2[n];
#pragma unroll
    for (int kb = 0; kb < 8; ++kb) {
      bf16x8 f;
#pragma unroll
      for (int j = 0; j < 8; ++j)
        f[j] = (short)f2b(Wn1[(kb * 32 + lg * 8 + j) * DD + n]);
      w1f[kb][nf] = f;
    }
#pragma unroll
    for (int kb = 0; kb < 4; ++kb) {
      bf16x8 f;
#pragma unroll
      for (int j = 0; j < 8; ++j)
        f[j] = (short)f2b(Wn2[(kb * 32 + lg * 8 + j) * DD + n]);
      w2f[kb][nf] = f;
    }
  }

  const int ntiles = (N + 63) >> 6;
  for (int tile = blockIdx.x; tile < ntiles; tile += gridDim.x) {
    const int nbase = tile << 6;
    __syncthreads();

#pragma unroll
    for (int it = 0; it < 16; ++it) {
      const int q = tid + it * 256;
      const int r = q >> 6;
      const int c = q & 63;
      int gr = nbase + r;
      if (gr >= N) gr = N - 1;
      float4 v;
      if (c < 32) v = *reinterpret_cast<const float4*>(x + (size_t)gr * DD + (c << 2));
      else        v = *reinterpret_cast<const float4*>(xout + (size_t)gr * DD + ((c - 32) << 2));
      unsigned short* dst = &A_lds[r][c << 2];
      dst[0] = f2b(v.x); dst[1] = f2b(v.y); dst[2] = f2b(v.z); dst[3] = f2b(v.w);
    }
    __syncthreads();

    f32x4 acc[4][2];
#pragma unroll
    for (int mf = 0; mf < 4; ++mf)
#pragma unroll
      for (int nf = 0; nf < 2; ++nf)
        acc[mf][nf] = (f32x4){0.f, 0.f, 0.f, 0.f};

#pragma unroll
    for (int kb = 0; kb < 8; ++kb) {
      bf16x8 a[4];
#pragma unroll
      for (int mf = 0; mf < 4; ++mf)
        a[mf] = *reinterpret_cast<const bf16x8*>(&A_lds[mf * 16 + lm][kb * 32 + lg * 8]);
#pragma unroll
      for (int mf = 0; mf < 4; ++mf)
#pragma unroll
        for (int nf = 0; nf < 2; ++nf)
          acc[mf][nf] = __builtin_amdgcn_mfma_f32_16x16x32_bf16(a[mf], w1f[kb][nf], acc[mf][nf], 0, 0, 0);
    }

#pragma unroll
    for (int mf = 0; mf < 4; ++mf)
#pragma unroll
      for (int nf = 0; nf < 2; ++nf)
#pragma unroll
        for (int rg = 0; rg < 4; ++rg) {
          const int m = mf * 16 + lg * 4 + rg;
          const int n = wv * 32 + nf * 16 + lm;
          float v = acc[mf][nf][rg] + b1[nf];
          h_lds[m][n] = f2b(v > 0.f ? v : 0.f);
        }
    __syncthreads();

    f32x4 acc2[4][2];
#pragma unroll
    for (int mf = 0; mf < 4; ++mf)
#pragma unroll
      for (int nf = 0; nf < 2; ++nf)
        acc2[mf][nf] = (f32x4){0.f, 0.f, 0.f, 0.f};

#pragma unroll
    for (int kb = 0; kb < 4; ++kb) {
      bf16x8 a[4];
#pragma unroll
      for (int mf = 0; mf < 4; ++mf)
        a[mf] = *reinterpret_cast<const bf16x8*>(&h_lds[mf * 16 + lm][kb * 32 + lg * 8]);
#pragma unroll
      for (int mf = 0; mf < 4; ++mf)
#pragma unroll
        for (int nf = 0; nf < 2; ++nf)
          acc2[mf][nf] = __builtin_amdgcn_mfma_f32_16x16x32_bf16(a[mf], w2f[kb][nf], acc2[mf][nf], 0, 0, 0);
    }

#pragma unroll
    for (int mf = 0; mf < 4; ++mf)
#pragma unroll
      for (int rg = 0; rg < 4; ++rg) {
        const int gm = nbase + mf * 16 + lg * 4 + rg;
        if (gm < N) {
#pragma unroll
          for (int nf = 0; nf < 2; ++nf) {
            const int n = wv * 32 + nf * 16 + lm;
            xout[(size_t)gm * DD + n] = acc2[mf][nf][rg] + b2[nf];
          }
        }
      }
  }
}

extern "C" void kernel_launch(void* const* d_in, const int* in_sizes, int n_in,
                              void* d_out, int out_size, void* d_ws, size_t ws_size,
                              hipStream_t stream) {
  const float* x   = (const float*)d_in[0];
  const int*   ei  = (const int*)d_in[1];
  const float* ea  = (const float*)d_in[2];
  const float* We1 = (const float*)d_in[3];
  const float* be1 = (const float*)d_in[4];
  const float* We2 = (const float*)d_in[5];
  const float* be2 = (const float*)d_in[6];
  const float* Wn1 = (const float*)d_in[7];
  const float* bn1 = (const float*)d_in[8];
  const float* Wn2 = (const float*)d_in[9];
  const float* bn2 = (const float*)d_in[10];

  const int N = in_sizes[0] / DD;   // 50000
  const int E = in_sizes[2] / DD;   // 600000

  float* out   = (float*)d_out;
  float* xout  = out;                    // x_out; early: PQ bf16 scratch
  float* e_out = out + (size_t)N * DD;   // e output

  unsigned short* pq = (unsigned short*)xout;  // [N][256] bf16, dead after edge kernel

  int* cnt  = (int*)d_ws;                // N
  int* off  = cnt + N;                   // N+1
  int* cur  = off + N + 1;               // N
  int* perm = cur + N;                   // E
  int* bsum = perm + E;                  // <=64

  const int SCAN_B = (N + 1023) / 1024;  // 49

  hipMemsetAsync(cnt, 0, (size_t)N * sizeof(int), stream);

  pq_kernel<<<(N + 63) / 64, 256, 0, stream>>>(x, We1, pq, N);

  count_kernel<<<(E + 255) / 256, 256, 0, stream>>>(ei, cnt, E);
  scan_a<<<SCAN_B, 256, 0, stream>>>(cnt, off, bsum, N);
  scan_b<<<1, 64, 0, stream>>>(bsum, SCAN_B);
  scan_c<<<SCAN_B, 256, 0, stream>>>(off, cur, bsum, N, E);
  fill_kernel<<<(E + 255) / 256, 256, 0, stream>>>(ei, cur, perm, E);

  edge_mlp_kernel<<<512, 256, 0, stream>>>(pq, ei, ea, We1, be1, We2, be2, e_out, E);

  agg_kernel<<<(N + 3) / 4, 256, 0, stream>>>(e_out, off, perm, xout, N);

  const int node_tiles = (N + 63) / 64;
  node_mlp_kernel<<<node_tiles, 256, 0, stream>>>(x, Wn1, bn1, Wn2, bn2, xout, N);
}

// Round 8
// 510.473 us; speedup vs baseline: 1.2783x; 1.2783x over previous
//
#include <hip/hip_runtime.h>
#include <hip/hip_bf16.h>

#define DD 128

typedef short bf16x8 __attribute__((ext_vector_type(8)));
typedef float f32x4 __attribute__((ext_vector_type(4)));

__device__ __forceinline__ unsigned short f2b(float f) {
  unsigned int u = __float_as_uint(f);
  u = u + 0x7FFFu + ((u >> 16) & 1u);
  return (unsigned short)(u >> 16);
}
__device__ __forceinline__ float b2f(unsigned short u) {
  return __uint_as_float((unsigned int)u << 16);
}

// ---------------- per-node in-degree ----------------
__global__ void count_kernel(const int* __restrict__ ei, int* __restrict__ cnt, int E) {
  int i = blockIdx.x * blockDim.x + threadIdx.x;
  if (i < E) atomicAdd(&cnt[ei[E + i]], 1);
}

// ---------------- prefix scan (3 kernels) ----------------
__global__ __launch_bounds__(256) void scan_a(const int* __restrict__ cnt,
                                              int* __restrict__ off,
                                              int* __restrict__ bsum, int N) {
  __shared__ int wsum[4];
  const int t = threadIdx.x;
  const int i0 = blockIdx.x * 1024 + t * 4;
  int4 v = {0, 0, 0, 0};
  if (i0 + 3 < N) v = *reinterpret_cast<const int4*>(cnt + i0);
  else {
    if (i0 < N)     v.x = cnt[i0];
    if (i0 + 1 < N) v.y = cnt[i0 + 1];
    if (i0 + 2 < N) v.z = cnt[i0 + 2];
    if (i0 + 3 < N) v.w = cnt[i0 + 3];
  }
  const int s1 = v.x, s2 = s1 + v.y, s3 = s2 + v.z, tot = s3 + v.w;
  const int lane = t & 63, wv = t >> 6;
  int sc = tot;
#pragma unroll
  for (int d = 1; d < 64; d <<= 1) {
    int u = __shfl_up(sc, d);
    if (lane >= d) sc += u;
  }
  if (lane == 63) wsum[wv] = sc;
  __syncthreads();
  int wpre = 0;
  for (int w = 0; w < wv; ++w) wpre += wsum[w];
  const int excl = wpre + sc - tot;
  if (i0 < N)     off[i0]     = excl;
  if (i0 + 1 < N) off[i0 + 1] = excl + s1;
  if (i0 + 2 < N) off[i0 + 2] = excl + s2;
  if (i0 + 3 < N) off[i0 + 3] = excl + s3;
  if (t == 255) bsum[blockIdx.x] = wpre + sc;
}

__global__ void scan_b(int* __restrict__ bsum, int B) {
  const int t = threadIdx.x;
  const int v0 = (t < B) ? bsum[t] : 0;
  int v = v0;
#pragma unroll
  for (int d = 1; d < 64; d <<= 1) {
    int u = __shfl_up(v, d);
    if (t >= d) v += u;
  }
  if (t < B) bsum[t] = v - v0;
}

__global__ __launch_bounds__(256) void scan_c(int* __restrict__ off, int* __restrict__ cur,
                                              const int* __restrict__ bsum, int N, int E) {
  const int t = threadIdx.x;
  const int add = bsum[blockIdx.x];
  const int i0 = blockIdx.x * 1024 + t * 4;
#pragma unroll
  for (int k = 0; k < 4; ++k) {
    const int i = i0 + k;
    if (i < N) {
      const int o = off[i] + add;
      off[i] = o;
      cur[i] = o;
    }
  }
  if (blockIdx.x == 0 && t == 0) off[N] = E;
}

__global__ void fill_kernel(const int* __restrict__ ei, int* __restrict__ cur,
                            int* __restrict__ perm, int E) {
  int i = blockIdx.x * blockDim.x + threadIdx.x;
  if (i < E) {
    const int d = ei[E + i];
    const int pos = atomicAdd(&cur[d], 1);
    perm[pos] = i;
  }
}

// ---------------- PQ precompute: PQ = x @ [W_a | W_b]  (bf16 out) ----------------
__global__ __launch_bounds__(256, 2) void pq_kernel(
    const float* __restrict__ x,
    const float* __restrict__ We1,
    unsigned short* __restrict__ pq,
    int N)
{
  __shared__ __align__(16) unsigned short x_lds[64][128];

  const int tid  = threadIdx.x;
  const int wv   = tid >> 6;
  const int lane = tid & 63;
  const int lg   = lane >> 4;
  const int lm   = lane & 15;

  bf16x8 wf[4][4];
#pragma unroll
  for (int nf = 0; nf < 4; ++nf) {
    const int n    = wv * 64 + nf * 16 + lm;
    const int col  = n & 127;
    const int kro  = (n >> 7) * 128;
#pragma unroll
    for (int kb = 0; kb < 4; ++kb) {
      bf16x8 f;
#pragma unroll
      for (int j = 0; j < 8; ++j)
        f[j] = (short)f2b(We1[(kro + kb * 32 + lg * 8 + j) * DD + col]);
      wf[kb][nf] = f;
    }
  }

  const int nbase = blockIdx.x * 64;

#pragma unroll
  for (int it = 0; it < 4; ++it) {
    const int q = tid + it * 256;
    const int r = q >> 4;
    const int c = q & 15;
    int gr = nbase + r; if (gr >= N) gr = N - 1;
    const float* p = x + (size_t)gr * DD + c * 8;
    const float4 va = *reinterpret_cast<const float4*>(p);
    const float4 vb = *reinterpret_cast<const float4*>(p + 4);
    bf16x8 o;
    o[0] = (short)f2b(va.x); o[1] = (short)f2b(va.y);
    o[2] = (short)f2b(va.z); o[3] = (short)f2b(va.w);
    o[4] = (short)f2b(vb.x); o[5] = (short)f2b(vb.y);
    o[6] = (short)f2b(vb.z); o[7] = (short)f2b(vb.w);
    *reinterpret_cast<bf16x8*>(&x_lds[r][(c ^ (r & 7)) * 8]) = o;
  }
  __syncthreads();

  f32x4 acc[4][4];
#pragma unroll
  for (int mf = 0; mf < 4; ++mf)
#pragma unroll
    for (int nf = 0; nf < 4; ++nf)
      acc[mf][nf] = (f32x4){0.f, 0.f, 0.f, 0.f};

#pragma unroll
  for (int kb = 0; kb < 4; ++kb) {
    bf16x8 a[4];
#pragma unroll
    for (int mf = 0; mf < 4; ++mf) {
      const int r = mf * 16 + lm;
      a[mf] = *reinterpret_cast<const bf16x8*>(&x_lds[r][((kb * 4 + lg) ^ (r & 7)) * 8]);
    }
#pragma unroll
    for (int mf = 0; mf < 4; ++mf)
#pragma unroll
      for (int nf = 0; nf < 4; ++nf)
        acc[mf][nf] = __builtin_amdgcn_mfma_f32_16x16x32_bf16(a[mf], wf[kb][nf], acc[mf][nf], 0, 0, 0);
  }

#pragma unroll
  for (int mf = 0; mf < 4; ++mf)
#pragma unroll
    for (int rg = 0; rg < 4; ++rg) {
      const int gm = nbase + mf * 16 + lg * 4 + rg;
      if (gm < N) {
#pragma unroll
        for (int nf = 0; nf < 4; ++nf)
          pq[(size_t)gm * 256 + wv * 64 + nf * 16 + lm] = f2b(acc[mf][nf][rg]);
      }
    }
}

// ---------------- edge MLP: r5 structure + T14 async ea prefetch, 4 blk/CU ----
// E is a multiple of 64 (600000 = 9375*64) — no tail handling.
__global__ __launch_bounds__(256, 4) void edge_mlp_kernel(
    const unsigned short* __restrict__ pq,   // [N][256] bf16: [P|Q]
    const int* __restrict__ ei,              // [2][E]
    const float* __restrict__ ea,            // [E][128] f32
    const float* __restrict__ We1,           // rows 256..383 = W_c
    const float* __restrict__ be1,
    const float* __restrict__ We2,
    const float* __restrict__ be2,
    float* __restrict__ e_out,               // [E][128] f32
    int E)
{
  __shared__ __align__(16) unsigned short ea_lds[64][128];  // chunk-swizzled
  __shared__ __align__(16) unsigned short h_lds[64][136];   // +8 pad (r3/r5 layout)
  __shared__ int srcs[2][64], dsts[2][64];

  const int tid  = threadIdx.x;
  const int wv   = tid >> 6;
  const int lane = tid & 63;
  const int lg   = lane >> 4;
  const int lm   = lane & 15;

  // ---- weight fragments: W_c (We1 rows 256..383) and We2; scalar biases ----
  bf16x8 w1f[4][2];
  bf16x8 w2f[4][2];
  float b1[2], b2[2];
#pragma unroll
  for (int nf = 0; nf < 2; ++nf) {
    const int n = wv * 32 + nf * 16 + lm;
    b1[nf] = be1[n];
    b2[nf] = be2[n];
#pragma unroll
    for (int kb = 0; kb < 4; ++kb) {
      bf16x8 f;
#pragma unroll
      for (int j = 0; j < 8; ++j)
        f[j] = (short)f2b(We1[(256 + kb * 32 + lg * 8 + j) * DD + n]);
      w1f[kb][nf] = f;
    }
#pragma unroll
    for (int kb = 0; kb < 4; ++kb) {
      bf16x8 f;
#pragma unroll
      for (int j = 0; j < 8; ++j)
        f[j] = (short)f2b(We2[(kb * 32 + lg * 8 + j) * DD + n]);
      w2f[kb][nf] = f;
    }
  }

  const int ntiles = E >> 6;
  const int stride = gridDim.x;

  // ---- prologue: issue tile0 ea loads + tile0 indices ----
  int tile = blockIdx.x;
  float4 va[4], vb[4];
  {
    const int eb = tile << 6;
#pragma unroll
    for (int it = 0; it < 4; ++it) {
      const int q = tid + it * 256;
      const float* p = ea + (size_t)(eb + (q >> 4)) * DD + (q & 15) * 8;
      va[it] = *reinterpret_cast<const float4*>(p);
      vb[it] = *reinterpret_cast<const float4*>(p + 4);
    }
    if (tid < 64)       srcs[0][tid]      = ei[eb + tid];
    else if (tid < 128) dsts[0][tid - 64] = ei[E + eb + tid - 64];
  }
  __syncthreads();

  int pb = 0;
  for (; tile < ntiles; tile += stride, pb ^= 1) {
    const int ebase = tile << 6;
    const int ntile = tile + stride;

    // ---- prefetch next tile's indices into the other buffer ----
    if (ntile < ntiles) {
      const int nb = ntile << 6;
      if (tid < 64)       srcs[pb ^ 1][tid]      = ei[nb + tid];
      else if (tid < 128) dsts[pb ^ 1][tid - 64] = ei[E + nb + tid - 64];
    }

    // ---- cvt prefetched ea regs -> swizzled LDS writes ----
#pragma unroll
    for (int it = 0; it < 4; ++it) {
      const int q = tid + it * 256;
      const int r = q >> 4;
      const int c = q & 15;
      bf16x8 o;
      o[0] = (short)f2b(va[it].x); o[1] = (short)f2b(va[it].y);
      o[2] = (short)f2b(va[it].z); o[3] = (short)f2b(va[it].w);
      o[4] = (short)f2b(vb[it].x); o[5] = (short)f2b(vb[it].y);
      o[6] = (short)f2b(vb[it].z); o[7] = (short)f2b(vb[it].w);
      *reinterpret_cast<bf16x8*>(&ea_lds[r][(c ^ (r & 7)) * 8]) = o;
    }
    __syncthreads();  // B1: ea_lds + next indices visible

    // ---- acc init = P[src] + Q[dest] (r5 exact) ----
    f32x4 acc[4][2];
#pragma unroll
    for (int mf = 0; mf < 4; ++mf)
#pragma unroll
      for (int rg = 0; rg < 4; ++rg) {
        const int m = mf * 16 + lg * 4 + rg;
        const size_t rs = (size_t)srcs[pb][m] * 256;
        const size_t rd = (size_t)dsts[pb][m] * 256;
#pragma unroll
        for (int nf = 0; nf < 2; ++nf) {
          const int n = wv * 32 + nf * 16 + lm;
          acc[mf][nf][rg] = b2f(pq[rs + n]) + b2f(pq[rd + 128 + n]);
        }
      }

    // ---- layer 1: acc += ea @ W_c  (K=128, r5 exact) ----
#pragma unroll
    for (int kb = 0; kb < 4; ++kb) {
      bf16x8 a[4];
#pragma unroll
      for (int mf = 0; mf < 4; ++mf) {
        const int r = mf * 16 + lm;
        a[mf] = *reinterpret_cast<const bf16x8*>(&ea_lds[r][((kb * 4 + lg) ^ (r & 7)) * 8]);
      }
#pragma unroll
      for (int mf = 0; mf < 4; ++mf)
#pragma unroll
        for (int nf = 0; nf < 2; ++nf)
          acc[mf][nf] = __builtin_amdgcn_mfma_f32_16x16x32_bf16(a[mf], w1f[kb][nf], acc[mf][nf], 0, 0, 0);
    }

    // ---- h = relu(acc + b1) -> h_lds (r5 exact) ----
#pragma unroll
    for (int mf = 0; mf < 4; ++mf)
#pragma unroll
      for (int nf = 0; nf < 2; ++nf)
#pragma unroll
        for (int rg = 0; rg < 4; ++rg) {
          const int m = mf * 16 + lg * 4 + rg;
          const int n = wv * 32 + nf * 16 + lm;
          float v = acc[mf][nf][rg] + b1[nf];
          h_lds[m][n] = f2b(v > 0.f ? v : 0.f);
        }
    __syncthreads();  // B2: h_lds ready; ea_lds free

    // ---- T14: issue NEXT tile's ea loads (consumed next iteration) ----
    if (ntile < ntiles) {
      const int nb = ntile << 6;
#pragma unroll
      for (int it = 0; it < 4; ++it) {
        const int q = tid + it * 256;
        const float* p = ea + (size_t)(nb + (q >> 4)) * DD + (q & 15) * 8;
        va[it] = *reinterpret_cast<const float4*>(p);
        vb[it] = *reinterpret_cast<const float4*>(p + 4);
      }
    }

    // ---- layer 2: e = h @ We2 + be2 (r5 exact) ----
    f32x4 acc2[4][2];
#pragma unroll
    for (int mf = 0; mf < 4; ++mf)
#pragma unroll
      for (int nf = 0; nf < 2; ++nf)
        acc2[mf][nf] = (f32x4){0.f, 0.f, 0.f, 0.f};

#pragma unroll
    for (int kb = 0; kb < 4; ++kb) {
      bf16x8 a[4];
#pragma unroll
      for (int mf = 0; mf < 4; ++mf)
        a[mf] = *reinterpret_cast<const bf16x8*>(&h_lds[mf * 16 + lm][kb * 32 + lg * 8]);
#pragma unroll
      for (int mf = 0; mf < 4; ++mf)
#pragma unroll
        for (int nf = 0; nf < 2; ++nf)
          acc2[mf][nf] = __builtin_amdgcn_mfma_f32_16x16x32_bf16(a[mf], w2f[kb][nf], acc2[mf][nf], 0, 0, 0);
    }

    // ---- epilogue: write e (r5 exact) ----
#pragma unroll
    for (int mf = 0; mf < 4; ++mf)
#pragma unroll
      for (int rg = 0; rg < 4; ++rg) {
        const int gm = ebase + mf * 16 + lg * 4 + rg;
#pragma unroll
        for (int nf = 0; nf < 2; ++nf) {
          const int n = wv * 32 + nf * 16 + lm;
          e_out[(size_t)gm * DD + n] = acc2[mf][nf][rg] + b2[nf];
        }
      }
  }
}

// ---------------- CSR scatter-mean: wave per node, 8-deep batched gathers ----
__global__ __launch_bounds__(256) void agg_kernel(const float* __restrict__ e_out,
                                                  const int* __restrict__ off,
                                                  const int* __restrict__ perm,
                                                  float* __restrict__ agg, int N) {
  const int wv   = threadIdx.x >> 6;
  const int lane = threadIdx.x & 63;
  const int nid  = blockIdx.x * 4 + wv;
  if (nid >= N) return;
  const int o0 = off[nid], o1 = off[nid + 1];
  float sx = 0.f, sy = 0.f;
  int j = o0;
  for (; j + 8 <= o1; j += 8) {
    int r[8];
#pragma unroll
    for (int k = 0; k < 8; ++k) r[k] = perm[j + k];
    float2 v[8];
#pragma unroll
    for (int k = 0; k < 8; ++k)
      v[k] = *reinterpret_cast<const float2*>(e_out + (size_t)r[k] * DD + (lane << 1));
#pragma unroll
    for (int k = 0; k < 8; ++k) { sx += v[k].x; sy += v[k].y; }
  }
  if (j + 4 <= o1) {
    int r[4];
#pragma unroll
    for (int k = 0; k < 4; ++k) r[k] = perm[j + k];
    float2 v[4];
#pragma unroll
    for (int k = 0; k < 4; ++k)
      v[k] = *reinterpret_cast<const float2*>(e_out + (size_t)r[k] * DD + (lane << 1));
#pragma unroll
    for (int k = 0; k < 4; ++k) { sx += v[k].x; sy += v[k].y; }
    j += 4;
  }
  for (; j < o1; ++j) {
    const int r = perm[j];
    const float2 v = *reinterpret_cast<const float2*>(e_out + (size_t)r * DD + (lane << 1));
    sx += v.x; sy += v.y;
  }
  const int deg = o1 - o0;
  const float inv = deg > 0 ? 1.f / (float)deg : 0.f;
  float2 o;
  o.x = sx * inv;
  o.y = sy * inv;
  *reinterpret_cast<float2*>(agg + (size_t)nid * DD + (lane << 1)) = o;
}

// ---------------- node MLP (r5 exact) ----------------
__global__ __launch_bounds__(256, 2) void node_mlp_kernel(
    const float* __restrict__ x,
    const float* __restrict__ Wn1,
    const float* __restrict__ bn1,
    const float* __restrict__ Wn2,
    const float* __restrict__ bn2,
    float* __restrict__ xout,        // in: agg mean, out: x_out
    int N)
{
  __shared__ __align__(16) unsigned short A_lds[64][264];
  __shared__ __align__(16) unsigned short h_lds[64][136];

  const int tid  = threadIdx.x;
  const int wv   = tid >> 6;
  const int lane = tid & 63;
  const int lg   = lane >> 4;
  const int lm   = lane & 15;

  bf16x8 w1f[8][2];
  bf16x8 w2f[4][2];
  float b1[2], b2[2];
#pragma unroll
  for (int nf = 0; nf < 2; ++nf) {
    const int n = wv * 32 + nf * 16 + lm;
    b1[nf] = bn1[n];
    b2[nf] = bn2[n];
#pragma unroll
    for (int kb = 0; kb < 8; ++kb) {
      bf16x8 f;
#pragma unroll
      for (int j = 0; j < 8; ++j)
        f[j] = (short)f2b(Wn1[(kb * 32 + lg * 8 + j) * DD + n]);
      w1f[kb][nf] = f;
    }
#pragma unroll
    for (int kb = 0; kb < 4; ++kb) {
      bf16x8 f;
#pragma unroll
      for (int j = 0; j < 8; ++j)
        f[j] = (short)f2b(Wn2[(kb * 32 + lg * 8 + j) * DD + n]);
      w2f[kb][nf] = f;
    }
  }

  const int ntiles = (N + 63) >> 6;
  for (int tile = blockIdx.x; tile < ntiles; tile += gridDim.x) {
    const int nbase = tile << 6;
    __syncthreads();

#pragma unroll
    for (int it = 0; it < 16; ++it) {
      const int q = tid + it * 256;
      const int r = q >> 6;
      const int c = q & 63;
      int gr = nbase + r;
      if (gr >= N) gr = N - 1;
      float4 v;
      if (c < 32) v = *reinterpret_cast<const float4*>(x + (size_t)gr * DD + (c << 2));
      else        v = *reinterpret_cast<const float4*>(xout + (size_t)gr * DD + ((c - 32) << 2));
      unsigned short* dst = &A_lds[r][c << 2];
      dst[0] = f2b(v.x); dst[1] = f2b(v.y); dst[2] = f2b(v.z); dst[3] = f2b(v.w);
    }
    __syncthreads();

    f32x4 acc[4][2];
#pragma unroll
    for (int mf = 0; mf < 4; ++mf)
#pragma unroll
      for (int nf = 0; nf < 2; ++nf)
        acc[mf][nf] = (f32x4){0.f, 0.f, 0.f, 0.f};

#pragma unroll
    for (int kb = 0; kb < 8; ++kb) {
      bf16x8 a[4];
#pragma unroll
      for (int mf = 0; mf < 4; ++mf)
        a[mf] = *reinterpret_cast<const bf16x8*>(&A_lds[mf * 16 + lm][kb * 32 + lg * 8]);
#pragma unroll
      for (int mf = 0; mf < 4; ++mf)
#pragma unroll
        for (int nf = 0; nf < 2; ++nf)
          acc[mf][nf] = __builtin_amdgcn_mfma_f32_16x16x32_bf16(a[mf], w1f[kb][nf], acc[mf][nf], 0, 0, 0);
    }

#pragma unroll
    for (int mf = 0; mf < 4; ++mf)
#pragma unroll
      for (int nf = 0; nf < 2; ++nf)
#pragma unroll
        for (int rg = 0; rg < 4; ++rg) {
          const int m = mf * 16 + lg * 4 + rg;
          const int n = wv * 32 + nf * 16 + lm;
          float v = acc[mf][nf][rg] + b1[nf];
          h_lds[m][n] = f2b(v > 0.f ? v : 0.f);
        }
    __syncthreads();

    f32x4 acc2[4][2];
#pragma unroll
    for (int mf = 0; mf < 4; ++mf)
#pragma unroll
      for (int nf = 0; nf < 2; ++nf)
        acc2[mf][nf] = (f32x4){0.f, 0.f, 0.f, 0.f};

#pragma unroll
    for (int kb = 0; kb < 4; ++kb) {
      bf16x8 a[4];
#pragma unroll
      for (int mf = 0; mf < 4; ++mf)
        a[mf] = *reinterpret_cast<const bf16x8*>(&h_lds[mf * 16 + lm][kb * 32 + lg * 8]);
#pragma unroll
      for (int mf = 0; mf < 4; ++mf)
#pragma unroll
        for (int nf = 0; nf < 2; ++nf)
          acc2[mf][nf] = __builtin_amdgcn_mfma_f32_16x16x32_bf16(a[mf], w2f[kb][nf], acc2[mf][nf], 0, 0, 0);
    }

#pragma unroll
    for (int mf = 0; mf < 4; ++mf)
#pragma unroll
      for (int rg = 0; rg < 4; ++rg) {
        const int gm = nbase + mf * 16 + lg * 4 + rg;
        if (gm < N) {
#pragma unroll
          for (int nf = 0; nf < 2; ++nf) {
            const int n = wv * 32 + nf * 16 + lm;
            xout[(size_t)gm * DD + n] = acc2[mf][nf][rg] + b2[nf];
          }
        }
      }
  }
}

extern "C" void kernel_launch(void* const* d_in, const int* in_sizes, int n_in,
                              void* d_out, int out_size, void* d_ws, size_t ws_size,
                              hipStream_t stream) {
  const float* x   = (const float*)d_in[0];
  const int*   ei  = (const int*)d_in[1];
  const float* ea  = (const float*)d_in[2];
  const float* We1 = (const float*)d_in[3];
  const float* be1 = (const float*)d_in[4];
  const float* We2 = (const float*)d_in[5];
  const float* be2 = (const float*)d_in[6];
  const float* Wn1 = (const float*)d_in[7];
  const float* bn1 = (const float*)d_in[8];
  const float* Wn2 = (const float*)d_in[9];
  const float* bn2 = (const float*)d_in[10];

  const int N = in_sizes[0] / DD;   // 50000
  const int E = in_sizes[2] / DD;   // 600000

  float* out   = (float*)d_out;
  float* xout  = out;                    // x_out; early: PQ bf16 scratch
  float* e_out = out + (size_t)N * DD;   // e output

  unsigned short* pq = (unsigned short*)xout;  // [N][256] bf16, dead after edge kernel

  int* cnt  = (int*)d_ws;                // N
  int* off  = cnt + N;                   // N+1
  int* cur  = off + N + 1;               // N
  int* perm = cur + N;                   // E
  int* bsum = perm + E;                  // <=64

  const int SCAN_B = (N + 1023) / 1024;  // 49

  hipMemsetAsync(cnt, 0, (size_t)N * sizeof(int), stream);

  pq_kernel<<<(N + 63) / 64, 256, 0, stream>>>(x, We1, pq, N);

  count_kernel<<<(E + 255) / 256, 256, 0, stream>>>(ei, cnt, E);
  scan_a<<<SCAN_B, 256, 0, stream>>>(cnt, off, bsum, N);
  scan_b<<<1, 64, 0, stream>>>(bsum, SCAN_B);
  scan_c<<<SCAN_B, 256, 0, stream>>>(off, cur, bsum, N, E);
  fill_kernel<<<(E + 255) / 256, 256, 0, stream>>>(ei, cur, perm, E);

  edge_mlp_kernel<<<2048, 256, 0, stream>>>(pq, ei, ea, We1, be1, We2, be2, e_out, E);

  agg_kernel<<<(N + 3) / 4, 256, 0, stream>>>(e_out, off, perm, xout, N);

  const int node_tiles = (N + 63) / 64;
  node_mlp_kernel<<<node_tiles, 256, 0, stream>>>(x, Wn1, bn1, Wn2, bn2, xout, N);
}

// Round 9
// 471.933 us; speedup vs baseline: 1.3827x; 1.0817x over previous
//
#include <hip/hip_runtime.h>
#include <hip/hip_bf16.h>

#define DD 128

typedef short bf16x8 __attribute__((ext_vector_type(8)));
typedef float f32x4 __attribute__((ext_vector_type(4)));

__device__ __forceinline__ unsigned short f2b(float f) {
  unsigned int u = __float_as_uint(f);
  u = u + 0x7FFFu + ((u >> 16) & 1u);
  return (unsigned short)(u >> 16);
}
__device__ __forceinline__ float b2f(unsigned short u) {
  return __uint_as_float((unsigned int)u << 16);
}

// ---------------- per-node in-degree ----------------
__global__ void count_kernel(const int* __restrict__ ei, int* __restrict__ cnt, int E) {
  int i = blockIdx.x * blockDim.x + threadIdx.x;
  if (i < E) atomicAdd(&cnt[ei[E + i]], 1);
}

// ---------------- prefix scan (3 kernels) ----------------
__global__ __launch_bounds__(256) void scan_a(const int* __restrict__ cnt,
                                              int* __restrict__ off,
                                              int* __restrict__ bsum, int N) {
  __shared__ int wsum[4];
  const int t = threadIdx.x;
  const int i0 = blockIdx.x * 1024 + t * 4;
  int4 v = {0, 0, 0, 0};
  if (i0 + 3 < N) v = *reinterpret_cast<const int4*>(cnt + i0);
  else {
    if (i0 < N)     v.x = cnt[i0];
    if (i0 + 1 < N) v.y = cnt[i0 + 1];
    if (i0 + 2 < N) v.z = cnt[i0 + 2];
    if (i0 + 3 < N) v.w = cnt[i0 + 3];
  }
  const int s1 = v.x, s2 = s1 + v.y, s3 = s2 + v.z, tot = s3 + v.w;
  const int lane = t & 63, wv = t >> 6;
  int sc = tot;
#pragma unroll
  for (int d = 1; d < 64; d <<= 1) {
    int u = __shfl_up(sc, d);
    if (lane >= d) sc += u;
  }
  if (lane == 63) wsum[wv] = sc;
  __syncthreads();
  int wpre = 0;
  for (int w = 0; w < wv; ++w) wpre += wsum[w];
  const int excl = wpre + sc - tot;
  if (i0 < N)     off[i0]     = excl;
  if (i0 + 1 < N) off[i0 + 1] = excl + s1;
  if (i0 + 2 < N) off[i0 + 2] = excl + s2;
  if (i0 + 3 < N) off[i0 + 3] = excl + s3;
  if (t == 255) bsum[blockIdx.x] = wpre + sc;
}

__global__ void scan_b(int* __restrict__ bsum, int B) {
  const int t = threadIdx.x;
  const int v0 = (t < B) ? bsum[t] : 0;
  int v = v0;
#pragma unroll
  for (int d = 1; d < 64; d <<= 1) {
    int u = __shfl_up(v, d);
    if (t >= d) v += u;
  }
  if (t < B) bsum[t] = v - v0;
}

__global__ __launch_bounds__(256) void scan_c(int* __restrict__ off, int* __restrict__ cur,
                                              const int* __restrict__ bsum, int N, int E) {
  const int t = threadIdx.x;
  const int add = bsum[blockIdx.x];
  const int i0 = blockIdx.x * 1024 + t * 4;
#pragma unroll
  for (int k = 0; k < 4; ++k) {
    const int i = i0 + k;
    if (i < N) {
      const int o = off[i] + add;
      off[i] = o;
      cur[i] = o;
    }
  }
  if (blockIdx.x == 0 && t == 0) off[N] = E;
}

__global__ void fill_kernel(const int* __restrict__ ei, int* __restrict__ cur,
                            int* __restrict__ perm, int E) {
  int i = blockIdx.x * blockDim.x + threadIdx.x;
  if (i < E) {
    const int d = ei[E + i];
    const int pos = atomicAdd(&cur[d], 1);
    perm[pos] = i;
  }
}

// ---------------- PQ precompute: PQ = x @ [W_a | W_b]  (bf16 out) ----------------
__global__ __launch_bounds__(256, 2) void pq_kernel(
    const float* __restrict__ x,
    const float* __restrict__ We1,
    unsigned short* __restrict__ pq,
    int N)
{
  __shared__ __align__(16) unsigned short x_lds[64][128];

  const int tid  = threadIdx.x;
  const int wv   = tid >> 6;
  const int lane = tid & 63;
  const int lg   = lane >> 4;
  const int lm   = lane & 15;

  bf16x8 wf[4][4];
#pragma unroll
  for (int nf = 0; nf < 4; ++nf) {
    const int n    = wv * 64 + nf * 16 + lm;
    const int col  = n & 127;
    const int kro  = (n >> 7) * 128;
#pragma unroll
    for (int kb = 0; kb < 4; ++kb) {
      bf16x8 f;
#pragma unroll
      for (int j = 0; j < 8; ++j)
        f[j] = (short)f2b(We1[(kro + kb * 32 + lg * 8 + j) * DD + col]);
      wf[kb][nf] = f;
    }
  }

  const int nbase = blockIdx.x * 64;

#pragma unroll
  for (int it = 0; it < 4; ++it) {
    const int q = tid + it * 256;
    const int r = q >> 4;
    const int c = q & 15;
    int gr = nbase + r; if (gr >= N) gr = N - 1;
    const float* p = x + (size_t)gr * DD + c * 8;
    const float4 va = *reinterpret_cast<const float4*>(p);
    const float4 vb = *reinterpret_cast<const float4*>(p + 4);
    bf16x8 o;
    o[0] = (short)f2b(va.x); o[1] = (short)f2b(va.y);
    o[2] = (short)f2b(va.z); o[3] = (short)f2b(va.w);
    o[4] = (short)f2b(vb.x); o[5] = (short)f2b(vb.y);
    o[6] = (short)f2b(vb.z); o[7] = (short)f2b(vb.w);
    *reinterpret_cast<bf16x8*>(&x_lds[r][(c ^ (r & 7)) * 8]) = o;
  }
  __syncthreads();

  f32x4 acc[4][4];
#pragma unroll
  for (int mf = 0; mf < 4; ++mf)
#pragma unroll
    for (int nf = 0; nf < 4; ++nf)
      acc[mf][nf] = (f32x4){0.f, 0.f, 0.f, 0.f};

#pragma unroll
  for (int kb = 0; kb < 4; ++kb) {
    bf16x8 a[4];
#pragma unroll
    for (int mf = 0; mf < 4; ++mf) {
      const int r = mf * 16 + lm;
      a[mf] = *reinterpret_cast<const bf16x8*>(&x_lds[r][((kb * 4 + lg) ^ (r & 7)) * 8]);
    }
#pragma unroll
    for (int mf = 0; mf < 4; ++mf)
#pragma unroll
      for (int nf = 0; nf < 4; ++nf)
        acc[mf][nf] = __builtin_amdgcn_mfma_f32_16x16x32_bf16(a[mf], wf[kb][nf], acc[mf][nf], 0, 0, 0);
  }

#pragma unroll
  for (int mf = 0; mf < 4; ++mf)
#pragma unroll
    for (int rg = 0; rg < 4; ++rg) {
      const int gm = nbase + mf * 16 + lg * 4 + rg;
      if (gm < N) {
#pragma unroll
        for (int nf = 0; nf < 4; ++nf)
          pq[(size_t)gm * 256 + wv * 64 + nf * 16 + lm] = f2b(acc[mf][nf][rg]);
      }
    }
}

// ---------------- edge MLP (r5 exact body; only launch_bounds 3 -> 4) ----------
// E is a multiple of 64 (600000 = 9375*64) — no tail handling.
__global__ __launch_bounds__(256, 4) void edge_mlp_kernel(
    const unsigned short* __restrict__ pq,   // [N][256] bf16: [P|Q]
    const int* __restrict__ ei,              // [2][E]
    const float* __restrict__ ea,            // [E][128] f32
    const float* __restrict__ We1,           // rows 256..383 = W_c
    const float* __restrict__ be1,
    const float* __restrict__ We2,
    const float* __restrict__ be2,
    float* __restrict__ e_out,               // [E][128] f32
    int E)
{
  __shared__ __align__(16) unsigned short ea_lds[64][128];  // chunk-swizzled
  __shared__ __align__(16) unsigned short h_lds[64][136];   // +8 pad (r3 layout)
  __shared__ int srcs[64], dsts[64];

  const int tid  = threadIdx.x;
  const int wv   = tid >> 6;
  const int lane = tid & 63;
  const int lg   = lane >> 4;
  const int lm   = lane & 15;

  // ---- weight fragments: W_c (We1 rows 256..383) and We2; scalar biases ----
  bf16x8 w1f[4][2];
  bf16x8 w2f[4][2];
  float b1[2], b2[2];
#pragma unroll
  for (int nf = 0; nf < 2; ++nf) {
    const int n = wv * 32 + nf * 16 + lm;
    b1[nf] = be1[n];
    b2[nf] = be2[n];
#pragma unroll
    for (int kb = 0; kb < 4; ++kb) {
      bf16x8 f;
#pragma unroll
      for (int j = 0; j < 8; ++j)
        f[j] = (short)f2b(We1[(256 + kb * 32 + lg * 8 + j) * DD + n]);
      w1f[kb][nf] = f;
    }
#pragma unroll
    for (int kb = 0; kb < 4; ++kb) {
      bf16x8 f;
#pragma unroll
      for (int j = 0; j < 8; ++j)
        f[j] = (short)f2b(We2[(kb * 32 + lg * 8 + j) * DD + n]);
      w2f[kb][nf] = f;
    }
  }

  const int ntiles = E >> 6;
  for (int tile = blockIdx.x; tile < ntiles; tile += gridDim.x) {
    const int ebase = tile << 6;
    __syncthreads();  // previous tile's LDS readers done

    if (tid < 64)       srcs[tid]      = ei[ebase + tid];
    else if (tid < 128) dsts[tid - 64] = ei[E + ebase + tid - 64];
    __syncthreads();

    // ---- ea loads (bulk BW) ----
    float4 va[4], vb[4];
#pragma unroll
    for (int it = 0; it < 4; ++it) {
      const int q = tid + it * 256;
      const float* p = ea + (size_t)(ebase + (q >> 4)) * DD + (q & 15) * 8;
      va[it] = *reinterpret_cast<const float4*>(p);
      vb[it] = *reinterpret_cast<const float4*>(p + 4);
    }

    // ---- acc init = P[src] + Q[dest] (independent bf16 gathers, overlap ea) ----
    f32x4 acc[4][2];
#pragma unroll
    for (int mf = 0; mf < 4; ++mf)
#pragma unroll
      for (int rg = 0; rg < 4; ++rg) {
        const int m = mf * 16 + lg * 4 + rg;
        const size_t rs = (size_t)srcs[m] * 256;
        const size_t rd = (size_t)dsts[m] * 256;
#pragma unroll
        for (int nf = 0; nf < 2; ++nf) {
          const int n = wv * 32 + nf * 16 + lm;
          acc[mf][nf][rg] = b2f(pq[rs + n]) + b2f(pq[rd + 128 + n]);
        }
      }

    // ---- ea cvt + swizzled LDS writes ----
#pragma unroll
    for (int it = 0; it < 4; ++it) {
      const int q = tid + it * 256;
      const int r = q >> 4;
      const int c = q & 15;
      bf16x8 o;
      o[0] = (short)f2b(va[it].x); o[1] = (short)f2b(va[it].y);
      o[2] = (short)f2b(va[it].z); o[3] = (short)f2b(va[it].w);
      o[4] = (short)f2b(vb[it].x); o[5] = (short)f2b(vb[it].y);
      o[6] = (short)f2b(vb[it].z); o[7] = (short)f2b(vb[it].w);
      *reinterpret_cast<bf16x8*>(&ea_lds[r][(c ^ (r & 7)) * 8]) = o;
    }
    __syncthreads();

    // ---- layer 1: acc += ea @ W_c  (K=128) ----
#pragma unroll
    for (int kb = 0; kb < 4; ++kb) {
      bf16x8 a[4];
#pragma unroll
      for (int mf = 0; mf < 4; ++mf) {
        const int r = mf * 16 + lm;
        a[mf] = *reinterpret_cast<const bf16x8*>(&ea_lds[r][((kb * 4 + lg) ^ (r & 7)) * 8]);
      }
#pragma unroll
      for (int mf = 0; mf < 4; ++mf)
#pragma unroll
        for (int nf = 0; nf < 2; ++nf)
          acc[mf][nf] = __builtin_amdgcn_mfma_f32_16x16x32_bf16(a[mf], w1f[kb][nf], acc[mf][nf], 0, 0, 0);
    }

    // ---- h = relu(acc + b1) -> h_lds (r3 layout) ----
#pragma unroll
    for (int mf = 0; mf < 4; ++mf)
#pragma unroll
      for (int nf = 0; nf < 2; ++nf)
#pragma unroll
        for (int rg = 0; rg < 4; ++rg) {
          const int m = mf * 16 + lg * 4 + rg;
          const int n = wv * 32 + nf * 16 + lm;
          float v = acc[mf][nf][rg] + b1[nf];
          h_lds[m][n] = f2b(v > 0.f ? v : 0.f);
        }
    __syncthreads();

    // ---- layer 2: e = h @ We2 + be2 ----
    f32x4 acc2[4][2];
#pragma unroll
    for (int mf = 0; mf < 4; ++mf)
#pragma unroll
      for (int nf = 0; nf < 2; ++nf)
        acc2[mf][nf] = (f32x4){0.f, 0.f, 0.f, 0.f};

#pragma unroll
    for (int kb = 0; kb < 4; ++kb) {
      bf16x8 a[4];
#pragma unroll
      for (int mf = 0; mf < 4; ++mf)
        a[mf] = *reinterpret_cast<const bf16x8*>(&h_lds[mf * 16 + lm][kb * 32 + lg * 8]);
#pragma unroll
      for (int mf = 0; mf < 4; ++mf)
#pragma unroll
        for (int nf = 0; nf < 2; ++nf)
          acc2[mf][nf] = __builtin_amdgcn_mfma_f32_16x16x32_bf16(a[mf], w2f[kb][nf], acc2[mf][nf], 0, 0, 0);
    }

    // ---- epilogue: write e ----
#pragma unroll
    for (int mf = 0; mf < 4; ++mf)
#pragma unroll
      for (int rg = 0; rg < 4; ++rg) {
        const int gm = ebase + mf * 16 + lg * 4 + rg;
#pragma unroll
        for (int nf = 0; nf < 2; ++nf) {
          const int n = wv * 32 + nf * 16 + lm;
          e_out[(size_t)gm * DD + n] = acc2[mf][nf][rg] + b2[nf];
        }
      }
  }
}

// ---------------- CSR scatter-mean: wave per node, 8-deep batched gathers ----
__global__ __launch_bounds__(256) void agg_kernel(const float* __restrict__ e_out,
                                                  const int* __restrict__ off,
                                                  const int* __restrict__ perm,
                                                  float* __restrict__ agg, int N) {
  const int wv   = threadIdx.x >> 6;
  const int lane = threadIdx.x & 63;
  const int nid  = blockIdx.x * 4 + wv;
  if (nid >= N) return;
  const int o0 = off[nid], o1 = off[nid + 1];
  float sx = 0.f, sy = 0.f;
  int j = o0;
  for (; j + 8 <= o1; j += 8) {
    int r[8];
#pragma unroll
    for (int k = 0; k < 8; ++k) r[k] = perm[j + k];
    float2 v[8];
#pragma unroll
    for (int k = 0; k < 8; ++k)
      v[k] = *reinterpret_cast<const float2*>(e_out + (size_t)r[k] * DD + (lane << 1));
#pragma unroll
    for (int k = 0; k < 8; ++k) { sx += v[k].x; sy += v[k].y; }
  }
  if (j + 4 <= o1) {
    int r[4];
#pragma unroll
    for (int k = 0; k < 4; ++k) r[k] = perm[j + k];
    float2 v[4];
#pragma unroll
    for (int k = 0; k < 4; ++k)
      v[k] = *reinterpret_cast<const float2*>(e_out + (size_t)r[k] * DD + (lane << 1));
#pragma unroll
    for (int k = 0; k < 4; ++k) { sx += v[k].x; sy += v[k].y; }
    j += 4;
  }
  for (; j < o1; ++j) {
    const int r = perm[j];
    const float2 v = *reinterpret_cast<const float2*>(e_out + (size_t)r * DD + (lane << 1));
    sx += v.x; sy += v.y;
  }
  const int deg = o1 - o0;
  const float inv = deg > 0 ? 1.f / (float)deg : 0.f;
  float2 o;
  o.x = sx * inv;
  o.y = sy * inv;
  *reinterpret_cast<float2*>(agg + (size_t)nid * DD + (lane << 1)) = o;
}

// ---------------- node MLP (r5 exact) ----------------
__global__ __launch_bounds__(256, 2) void node_mlp_kernel(
    const float* __restrict__ x,
    const float* __restrict__ Wn1,
    const float* __restrict__ bn1,
    const float* __restrict__ Wn2,
    const float* __restrict__ bn2,
    float* __restrict__ xout,        // in: agg mean, out: x_out
    int N)
{
  __shared__ __align__(16) unsigned short A_lds[64][264];
  __shared__ __align__(16) unsigned short h_lds[64][136];

  const int tid  = threadIdx.x;
  const int wv   = tid >> 6;
  const int lane = tid & 63;
  const int lg   = lane >> 4;
  const int lm   = lane & 15;

  bf16x8 w1f[8][2];
  bf16x8 w2f[4][2];
  float b1[2], b2[2];
#pragma unroll
  for (int nf = 0; nf < 2; ++nf) {
    const int n = wv * 32 + nf * 16 + lm;
    b1[nf] = bn1[n];
    b2[nf] = bn2[n];
#pragma unroll
    for (int kb = 0; kb < 8; ++kb) {
      bf16x8 f;
#pragma unroll
      for (int j = 0; j < 8; ++j)
        f[j] = (short)f2b(Wn1[(kb * 32 + lg * 8 + j) * DD + n]);
      w1f[kb][nf] = f;
    }
#pragma unroll
    for (int kb = 0; kb < 4; ++kb) {
      bf16x8 f;
#pragma unroll
      for (int j = 0; j < 8; ++j)
        f[j] = (short)f2b(Wn2[(kb * 32 + lg * 8 + j) * DD + n]);
      w2f[kb][nf] = f;
    }
  }

  const int ntiles = (N + 63) >> 6;
  for (int tile = blockIdx.x; tile < ntiles; tile += gridDim.x) {
    const int nbase = tile << 6;
    __syncthreads();

#pragma unroll
    for (int it = 0; it < 16; ++it) {
      const int q = tid + it * 256;
      const int r = q >> 6;
      const int c = q & 63;
      int gr = nbase + r;
      if (gr >= N) gr = N - 1;
      float4 v;
      if (c < 32) v = *reinterpret_cast<const float4*>(x + (size_t)gr * DD + (c << 2));
      else        v = *reinterpret_cast<const float4*>(xout + (size_t)gr * DD + ((c - 32) << 2));
      unsigned short* dst = &A_lds[r][c << 2];
      dst[0] = f2b(v.x); dst[1] = f2b(v.y); dst[2] = f2b(v.z); dst[3] = f2b(v.w);
    }
    __syncthreads();

    f32x4 acc[4][2];
#pragma unroll
    for (int mf = 0; mf < 4; ++mf)
#pragma unroll
      for (int nf = 0; nf < 2; ++nf)
        acc[mf][nf] = (f32x4){0.f, 0.f, 0.f, 0.f};

#pragma unroll
    for (int kb = 0; kb < 8; ++kb) {
      bf16x8 a[4];
#pragma unroll
      for (int mf = 0; mf < 4; ++mf)
        a[mf] = *reinterpret_cast<const bf16x8*>(&A_lds[mf * 16 + lm][kb * 32 + lg * 8]);
#pragma unroll
      for (int mf = 0; mf < 4; ++mf)
#pragma unroll
        for (int nf = 0; nf < 2; ++nf)
          acc[mf][nf] = __builtin_amdgcn_mfma_f32_16x16x32_bf16(a[mf], w1f[kb][nf], acc[mf][nf], 0, 0, 0);
    }

#pragma unroll
    for (int mf = 0; mf < 4; ++mf)
#pragma unroll
      for (int nf = 0; nf < 2; ++nf)
#pragma unroll
        for (int rg = 0; rg < 4; ++rg) {
          const int m = mf * 16 + lg * 4 + rg;
          const int n = wv * 32 + nf * 16 + lm;
          float v = acc[mf][nf][rg] + b1[nf];
          h_lds[m][n] = f2b(v > 0.f ? v : 0.f);
        }
    __syncthreads();

    f32x4 acc2[4][2];
#pragma unroll
    for (int mf = 0; mf < 4; ++mf)
#pragma unroll
      for (int nf = 0; nf < 2; ++nf)
        acc2[mf][nf] = (f32x4){0.f, 0.f, 0.f, 0.f};

#pragma unroll
    for (int kb = 0; kb < 4; ++kb) {
      bf16x8 a[4];
#pragma unroll
      for (int mf = 0; mf < 4; ++mf)
        a[mf] = *reinterpret_cast<const bf16x8*>(&h_lds[mf * 16 + lm][kb * 32 + lg * 8]);
#pragma unroll
      for (int mf = 0; mf < 4; ++mf)
#pragma unroll
        for (int nf = 0; nf < 2; ++nf)
          acc2[mf][nf] = __builtin_amdgcn_mfma_f32_16x16x32_bf16(a[mf], w2f[kb][nf], acc2[mf][nf], 0, 0, 0);
    }

#pragma unroll
    for (int mf = 0; mf < 4; ++mf)
#pragma unroll
      for (int rg = 0; rg < 4; ++rg) {
        const int gm = nbase + mf * 16 + lg * 4 + rg;
        if (gm < N) {
#pragma unroll
          for (int nf = 0; nf < 2; ++nf) {
            const int n = wv * 32 + nf * 16 + lm;
            xout[(size_t)gm * DD + n] = acc2[mf][nf][rg] + b2[nf];
          }
        }
      }
  }
}

extern "C" void kernel_launch(void* const* d_in, const int* in_sizes, int n_in,
                              void* d_out, int out_size, void* d_ws, size_t ws_size,
                              hipStream_t stream) {
  const float* x   = (const float*)d_in[0];
  const int*   ei  = (const int*)d_in[1];
  const float* ea  = (const float*)d_in[2];
  const float* We1 = (const float*)d_in[3];
  const float* be1 = (const float*)d_in[4];
  const float* We2 = (const float*)d_in[5];
  const float* be2 = (const float*)d_in[6];
  const float* Wn1 = (const float*)d_in[7];
  const float* bn1 = (const float*)d_in[8];
  const float* Wn2 = (const float*)d_in[9];
  const float* bn2 = (const float*)d_in[10];

  const int N = in_sizes[0] / DD;   // 50000
  const int E = in_sizes[2] / DD;   // 600000

  float* out   = (float*)d_out;
  float* xout  = out;                    // x_out; early: PQ bf16 scratch
  float* e_out = out + (size_t)N * DD;   // e output

  unsigned short* pq = (unsigned short*)xout;  // [N][256] bf16, dead after edge kernel

  int* cnt  = (int*)d_ws;                // N
  int* off  = cnt + N;                   // N+1
  int* cur  = off + N + 1;               // N
  int* perm = cur + N;                   // E
  int* bsum = perm + E;                  // <=64

  const int SCAN_B = (N + 1023) / 1024;  // 49

  hipMemsetAsync(cnt, 0, (size_t)N * sizeof(int), stream);

  pq_kernel<<<(N + 63) / 64, 256, 0, stream>>>(x, We1, pq, N);

  count_kernel<<<(E + 255) / 256, 256, 0, stream>>>(ei, cnt, E);
  scan_a<<<SCAN_B, 256, 0, stream>>>(cnt, off, bsum, N);
  scan_b<<<1, 64, 0, stream>>>(bsum, SCAN_B);
  scan_c<<<SCAN_B, 256, 0, stream>>>(off, cur, bsum, N, E);
  fill_kernel<<<(E + 255) / 256, 256, 0, stream>>>(ei, cur, perm, E);

  edge_mlp_kernel<<<2048, 256, 0, stream>>>(pq, ei, ea, We1, be1, We2, be2, e_out, E);

  agg_kernel<<<(N + 3) / 4, 256, 0, stream>>>(e_out, off, perm, xout, N);

  const int node_tiles = (N + 63) / 64;
  node_mlp_kernel<<<node_tiles, 256, 0, stream>>>(x, Wn1, bn1, Wn2, bn2, xout, N);
}

// Round 10
// 423.105 us; speedup vs baseline: 1.5423x; 1.1154x over previous
//
#include <hip/hip_runtime.h>
#include <hip/hip_bf16.h>

#define DD 128

typedef short bf16x8 __attribute__((ext_vector_type(8)));
typedef float f32x4 __attribute__((ext_vector_type(4)));

__device__ __forceinline__ unsigned short f2b(float f) {
  unsigned int u = __float_as_uint(f);
  u = u + 0x7FFFu + ((u >> 16) & 1u);
  return (unsigned short)(u >> 16);
}
__device__ __forceinline__ float b2f(unsigned short u) {
  return __uint_as_float((unsigned int)u << 16);
}

// ---------------- per-node in-degree ----------------
__global__ void count_kernel(const int* __restrict__ ei, int* __restrict__ cnt, int E) {
  int i = blockIdx.x * blockDim.x + threadIdx.x;
  if (i < E) atomicAdd(&cnt[ei[E + i]], 1);
}

// ---------------- prefix scan (3 kernels) ----------------
__global__ __launch_bounds__(256) void scan_a(const int* __restrict__ cnt,
                                              int* __restrict__ off,
                                              int* __restrict__ bsum, int N) {
  __shared__ int wsum[4];
  const int t = threadIdx.x;
  const int i0 = blockIdx.x * 1024 + t * 4;
  int4 v = {0, 0, 0, 0};
  if (i0 + 3 < N) v = *reinterpret_cast<const int4*>(cnt + i0);
  else {
    if (i0 < N)     v.x = cnt[i0];
    if (i0 + 1 < N) v.y = cnt[i0 + 1];
    if (i0 + 2 < N) v.z = cnt[i0 + 2];
    if (i0 + 3 < N) v.w = cnt[i0 + 3];
  }
  const int s1 = v.x, s2 = s1 + v.y, s3 = s2 + v.z, tot = s3 + v.w;
  const int lane = t & 63, wv = t >> 6;
  int sc = tot;
#pragma unroll
  for (int d = 1; d < 64; d <<= 1) {
    int u = __shfl_up(sc, d);
    if (lane >= d) sc += u;
  }
  if (lane == 63) wsum[wv] = sc;
  __syncthreads();
  int wpre = 0;
  for (int w = 0; w < wv; ++w) wpre += wsum[w];
  const int excl = wpre + sc - tot;
  if (i0 < N)     off[i0]     = excl;
  if (i0 + 1 < N) off[i0 + 1] = excl + s1;
  if (i0 + 2 < N) off[i0 + 2] = excl + s2;
  if (i0 + 3 < N) off[i0 + 3] = excl + s3;
  if (t == 255) bsum[blockIdx.x] = wpre + sc;
}

__global__ void scan_b(int* __restrict__ bsum, int B) {
  const int t = threadIdx.x;
  const int v0 = (t < B) ? bsum[t] : 0;
  int v = v0;
#pragma unroll
  for (int d = 1; d < 64; d <<= 1) {
    int u = __shfl_up(v, d);
    if (t >= d) v += u;
  }
  if (t < B) bsum[t] = v - v0;
}

__global__ __launch_bounds__(256) void scan_c(int* __restrict__ off, int* __restrict__ cur,
                                              const int* __restrict__ bsum, int N, int E) {
  const int t = threadIdx.x;
  const int add = bsum[blockIdx.x];
  const int i0 = blockIdx.x * 1024 + t * 4;
#pragma unroll
  for (int k = 0; k < 4; ++k) {
    const int i = i0 + k;
    if (i < N) {
      const int o = off[i] + add;
      off[i] = o;
      cur[i] = o;
    }
  }
  if (blockIdx.x == 0 && t == 0) off[N] = E;
}

__global__ void fill_kernel(const int* __restrict__ ei, int* __restrict__ cur,
                            int* __restrict__ perm, int E) {
  int i = blockIdx.x * blockDim.x + threadIdx.x;
  if (i < E) {
    const int d = ei[E + i];
    const int pos = atomicAdd(&cur[d], 1);
    perm[pos] = i;
  }
}

// ---------------- PQ precompute: PQ = x @ [W_a | W_b]  (bf16 out) ----------------
__global__ __launch_bounds__(256, 2) void pq_kernel(
    const float* __restrict__ x,
    const float* __restrict__ We1,
    unsigned short* __restrict__ pq,
    int N)
{
  __shared__ __align__(16) unsigned short x_lds[64][128];

  const int tid  = threadIdx.x;
  const int wv   = tid >> 6;
  const int lane = tid & 63;
  const int lg   = lane >> 4;
  const int lm   = lane & 15;

  bf16x8 wf[4][4];
#pragma unroll
  for (int nf = 0; nf < 4; ++nf) {
    const int n    = wv * 64 + nf * 16 + lm;
    const int col  = n & 127;
    const int kro  = (n >> 7) * 128;
#pragma unroll
    for (int kb = 0; kb < 4; ++kb) {
      bf16x8 f;
#pragma unroll
      for (int j = 0; j < 8; ++j)
        f[j] = (short)f2b(We1[(kro + kb * 32 + lg * 8 + j) * DD + col]);
      wf[kb][nf] = f;
    }
  }

  const int nbase = blockIdx.x * 64;

#pragma unroll
  for (int it = 0; it < 4; ++it) {
    const int q = tid + it * 256;
    const int r = q >> 4;
    const int c = q & 15;
    int gr = nbase + r; if (gr >= N) gr = N - 1;
    const float* p = x + (size_t)gr * DD + c * 8;
    const float4 va = *reinterpret_cast<const float4*>(p);
    const float4 vb = *reinterpret_cast<const float4*>(p + 4);
    bf16x8 o;
    o[0] = (short)f2b(va.x); o[1] = (short)f2b(va.y);
    o[2] = (short)f2b(va.z); o[3] = (short)f2b(va.w);
    o[4] = (short)f2b(vb.x); o[5] = (short)f2b(vb.y);
    o[6] = (short)f2b(vb.z); o[7] = (short)f2b(vb.w);
    *reinterpret_cast<bf16x8*>(&x_lds[r][(c ^ (r & 7)) * 8]) = o;
  }
  __syncthreads();

  f32x4 acc[4][4];
#pragma unroll
  for (int mf = 0; mf < 4; ++mf)
#pragma unroll
    for (int nf = 0; nf < 4; ++nf)
      acc[mf][nf] = (f32x4){0.f, 0.f, 0.f, 0.f};

#pragma unroll
  for (int kb = 0; kb < 4; ++kb) {
    bf16x8 a[4];
#pragma unroll
    for (int mf = 0; mf < 4; ++mf) {
      const int r = mf * 16 + lm;
      a[mf] = *reinterpret_cast<const bf16x8*>(&x_lds[r][((kb * 4 + lg) ^ (r & 7)) * 8]);
    }
#pragma unroll
    for (int mf = 0; mf < 4; ++mf)
#pragma unroll
      for (int nf = 0; nf < 4; ++nf)
        acc[mf][nf] = __builtin_amdgcn_mfma_f32_16x16x32_bf16(a[mf], wf[kb][nf], acc[mf][nf], 0, 0, 0);
  }

#pragma unroll
  for (int mf = 0; mf < 4; ++mf)
#pragma unroll
    for (int rg = 0; rg < 4; ++rg) {
      const int gm = nbase + mf * 16 + lg * 4 + rg;
      if (gm < N) {
#pragma unroll
        for (int nf = 0; nf < 4; ++nf)
          pq[(size_t)gm * 256 + wv * 64 + nf * 16 + lm] = f2b(acc[mf][nf][rg]);
      }
    }
}

// ---------------- edge MLP: r5 body, dbuf idx, 2 barriers/tile, (256,3) ----------
// E is a multiple of 64 (600000 = 9375*64) — no tail handling.
__global__ __launch_bounds__(256, 3) void edge_mlp_kernel(
    const unsigned short* __restrict__ pq,   // [N][256] bf16: [P|Q]
    const int* __restrict__ ei,              // [2][E]
    const float* __restrict__ ea,            // [E][128] f32
    const float* __restrict__ We1,           // rows 256..383 = W_c
    const float* __restrict__ be1,
    const float* __restrict__ We2,
    const float* __restrict__ be2,
    float* __restrict__ e_out,               // [E][128] f32
    int E)
{
  __shared__ __align__(16) unsigned short ea_lds[64][128];  // chunk-swizzled
  __shared__ __align__(16) unsigned short h_lds[64][136];   // +8 pad (r3 layout)
  __shared__ int srcs[2][64], dsts[2][64];

  const int tid  = threadIdx.x;
  const int wv   = tid >> 6;
  const int lane = tid & 63;
  const int lg   = lane >> 4;
  const int lm   = lane & 15;

  // ---- weight fragments: W_c (We1 rows 256..383) and We2; scalar biases ----
  bf16x8 w1f[4][2];
  bf16x8 w2f[4][2];
  float b1[2], b2[2];
#pragma unroll
  for (int nf = 0; nf < 2; ++nf) {
    const int n = wv * 32 + nf * 16 + lm;
    b1[nf] = be1[n];
    b2[nf] = be2[n];
#pragma unroll
    for (int kb = 0; kb < 4; ++kb) {
      bf16x8 f;
#pragma unroll
      for (int j = 0; j < 8; ++j)
        f[j] = (short)f2b(We1[(256 + kb * 32 + lg * 8 + j) * DD + n]);
      w1f[kb][nf] = f;
    }
#pragma unroll
    for (int kb = 0; kb < 4; ++kb) {
      bf16x8 f;
#pragma unroll
      for (int j = 0; j < 8; ++j)
        f[j] = (short)f2b(We2[(kb * 32 + lg * 8 + j) * DD + n]);
      w2f[kb][nf] = f;
    }
  }

  const int ntiles = E >> 6;
  const int stride = gridDim.x;
  int tile = blockIdx.x;

  // ---- prologue: indices for first tile ----
  if (tile < ntiles) {
    const int eb = tile << 6;
    if (tid < 64)       srcs[0][tid]      = ei[eb + tid];
    else if (tid < 128) dsts[0][tid - 64] = ei[E + eb + tid - 64];
  }
  __syncthreads();

  int pb = 0;
  for (; tile < ntiles; tile += stride, pb ^= 1) {
    const int ebase = tile << 6;

    // ---- 1) pq gathers first (random tail overlaps everything below) ----
    f32x4 acc[4][2];
#pragma unroll
    for (int mf = 0; mf < 4; ++mf)
#pragma unroll
      for (int rg = 0; rg < 4; ++rg) {
        const int m = mf * 16 + lg * 4 + rg;
        const size_t rs = (size_t)srcs[pb][m] * 256;
        const size_t rd = (size_t)dsts[pb][m] * 256;
#pragma unroll
        for (int nf = 0; nf < 2; ++nf) {
          const int n = wv * 32 + nf * 16 + lm;
          acc[mf][nf][rg] = b2f(pq[rs + n]) + b2f(pq[rd + 128 + n]);
        }
      }

    // ---- 2) ea loads (sequential stream) ----
    float4 va[4], vb[4];
#pragma unroll
    for (int it = 0; it < 4; ++it) {
      const int q = tid + it * 256;
      const float* p = ea + (size_t)(ebase + (q >> 4)) * DD + (q & 15) * 8;
      va[it] = *reinterpret_cast<const float4*>(p);
      vb[it] = *reinterpret_cast<const float4*>(p + 4);
    }

    // ---- 3) next tile's indices into the other buffer ----
    const int ntile = tile + stride;
    if (ntile < ntiles) {
      const int nb = ntile << 6;
      if (tid < 64)       srcs[pb ^ 1][tid]      = ei[nb + tid];
      else if (tid < 128) dsts[pb ^ 1][tid - 64] = ei[E + nb + tid - 64];
    }

    // ---- 4) ea cvt + swizzled LDS writes ----
#pragma unroll
    for (int it = 0; it < 4; ++it) {
      const int q = tid + it * 256;
      const int r = q >> 4;
      const int c = q & 15;
      bf16x8 o;
      o[0] = (short)f2b(va[it].x); o[1] = (short)f2b(va[it].y);
      o[2] = (short)f2b(va[it].z); o[3] = (short)f2b(va[it].w);
      o[4] = (short)f2b(vb[it].x); o[5] = (short)f2b(vb[it].y);
      o[6] = (short)f2b(vb[it].z); o[7] = (short)f2b(vb[it].w);
      *reinterpret_cast<bf16x8*>(&ea_lds[r][(c ^ (r & 7)) * 8]) = o;
    }
    __syncthreads();  // B1: ea_lds + next indices visible

    // ---- layer 1: acc += ea @ W_c  (K=128, r5 exact) ----
#pragma unroll
    for (int kb = 0; kb < 4; ++kb) {
      bf16x8 a[4];
#pragma unroll
      for (int mf = 0; mf < 4; ++mf) {
        const int r = mf * 16 + lm;
        a[mf] = *reinterpret_cast<const bf16x8*>(&ea_lds[r][((kb * 4 + lg) ^ (r & 7)) * 8]);
      }
#pragma unroll
      for (int mf = 0; mf < 4; ++mf)
#pragma unroll
        for (int nf = 0; nf < 2; ++nf)
          acc[mf][nf] = __builtin_amdgcn_mfma_f32_16x16x32_bf16(a[mf], w1f[kb][nf], acc[mf][nf], 0, 0, 0);
    }

    // ---- h = relu(acc + b1) -> h_lds (r5 exact) ----
#pragma unroll
    for (int mf = 0; mf < 4; ++mf)
#pragma unroll
      for (int nf = 0; nf < 2; ++nf)
#pragma unroll
        for (int rg = 0; rg < 4; ++rg) {
          const int m = mf * 16 + lg * 4 + rg;
          const int n = wv * 32 + nf * 16 + lm;
          float v = acc[mf][nf][rg] + b1[nf];
          h_lds[m][n] = f2b(v > 0.f ? v : 0.f);
        }
    __syncthreads();  // B2: h_lds ready

    // ---- layer 2: e = h @ We2 + be2 (r5 exact) ----
    f32x4 acc2[4][2];
#pragma unroll
    for (int mf = 0; mf < 4; ++mf)
#pragma unroll
      for (int nf = 0; nf < 2; ++nf)
        acc2[mf][nf] = (f32x4){0.f, 0.f, 0.f, 0.f};

#pragma unroll
    for (int kb = 0; kb < 4; ++kb) {
      bf16x8 a[4];
#pragma unroll
      for (int mf = 0; mf < 4; ++mf)
        a[mf] = *reinterpret_cast<const bf16x8*>(&h_lds[mf * 16 + lm][kb * 32 + lg * 8]);
#pragma unroll
      for (int mf = 0; mf < 4; ++mf)
#pragma unroll
        for (int nf = 0; nf < 2; ++nf)
          acc2[mf][nf] = __builtin_amdgcn_mfma_f32_16x16x32_bf16(a[mf], w2f[kb][nf], acc2[mf][nf], 0, 0, 0);
    }

    // ---- epilogue: write e (r5 exact) ----
#pragma unroll
    for (int mf = 0; mf < 4; ++mf)
#pragma unroll
      for (int rg = 0; rg < 4; ++rg) {
        const int gm = ebase + mf * 16 + lg * 4 + rg;
#pragma unroll
        for (int nf = 0; nf < 2; ++nf) {
          const int n = wv * 32 + nf * 16 + lm;
          e_out[(size_t)gm * DD + n] = acc2[mf][nf][rg] + b2[nf];
        }
      }
  }
}

// ---------------- CSR scatter-mean: wave per node, 8-deep batched gathers ----
__global__ __launch_bounds__(256) void agg_kernel(const float* __restrict__ e_out,
                                                  const int* __restrict__ off,
                                                  const int* __restrict__ perm,
                                                  float* __restrict__ agg, int N) {
  const int wv   = threadIdx.x >> 6;
  const int lane = threadIdx.x & 63;
  const int nid  = blockIdx.x * 4 + wv;
  if (nid >= N) return;
  const int o0 = off[nid], o1 = off[nid + 1];
  float sx = 0.f, sy = 0.f;
  int j = o0;
  for (; j + 8 <= o1; j += 8) {
    int r[8];
#pragma unroll
    for (int k = 0; k < 8; ++k) r[k] = perm[j + k];
    float2 v[8];
#pragma unroll
    for (int k = 0; k < 8; ++k)
      v[k] = *reinterpret_cast<const float2*>(e_out + (size_t)r[k] * DD + (lane << 1));
#pragma unroll
    for (int k = 0; k < 8; ++k) { sx += v[k].x; sy += v[k].y; }
  }
  if (j + 4 <= o1) {
    int r[4];
#pragma unroll
    for (int k = 0; k < 4; ++k) r[k] = perm[j + k];
    float2 v[4];
#pragma unroll
    for (int k = 0; k < 4; ++k)
      v[k] = *reinterpret_cast<const float2*>(e_out + (size_t)r[k] * DD + (lane << 1));
#pragma unroll
    for (int k = 0; k < 4; ++k) { sx += v[k].x; sy += v[k].y; }
    j += 4;
  }
  for (; j < o1; ++j) {
    const int r = perm[j];
    const float2 v = *reinterpret_cast<const float2*>(e_out + (size_t)r * DD + (lane << 1));
    sx += v.x; sy += v.y;
  }
  const int deg = o1 - o0;
  const float inv = deg > 0 ? 1.f / (float)deg : 0.f;
  float2 o;
  o.x = sx * inv;
  o.y = sy * inv;
  *reinterpret_cast<float2*>(agg + (size_t)nid * DD + (lane << 1)) = o;
}

// ---------------- node MLP (r5 exact) ----------------
__global__ __launch_bounds__(256, 2) void node_mlp_kernel(
    const float* __restrict__ x,
    const float* __restrict__ Wn1,
    const float* __restrict__ bn1,
    const float* __restrict__ Wn2,
    const float* __restrict__ bn2,
    float* __restrict__ xout,        // in: agg mean, out: x_out
    int N)
{
  __shared__ __align__(16) unsigned short A_lds[64][264];
  __shared__ __align__(16) unsigned short h_lds[64][136];

  const int tid  = threadIdx.x;
  const int wv   = tid >> 6;
  const int lane = tid & 63;
  const int lg   = lane >> 4;
  const int lm   = lane & 15;

  bf16x8 w1f[8][2];
  bf16x8 w2f[4][2];
  float b1[2], b2[2];
#pragma unroll
  for (int nf = 0; nf < 2; ++nf) {
    const int n = wv * 32 + nf * 16 + lm;
    b1[nf] = bn1[n];
    b2[nf] = bn2[n];
#pragma unroll
    for (int kb = 0; kb < 8; ++kb) {
      bf16x8 f;
#pragma unroll
      for (int j = 0; j < 8; ++j)
        f[j] = (short)f2b(Wn1[(kb * 32 + lg * 8 + j) * DD + n]);
      w1f[kb][nf] = f;
    }
#pragma unroll
    for (int kb = 0; kb < 4; ++kb) {
      bf16x8 f;
#pragma unroll
      for (int j = 0; j < 8; ++j)
        f[j] = (short)f2b(Wn2[(kb * 32 + lg * 8 + j) * DD + n]);
      w2f[kb][nf] = f;
    }
  }

  const int ntiles = (N + 63) >> 6;
  for (int tile = blockIdx.x; tile < ntiles; tile += gridDim.x) {
    const int nbase = tile << 6;
    __syncthreads();

#pragma unroll
    for (int it = 0; it < 16; ++it) {
      const int q = tid + it * 256;
      const int r = q >> 6;
      const int c = q & 63;
      int gr = nbase + r;
      if (gr >= N) gr = N - 1;
      float4 v;
      if (c < 32) v = *reinterpret_cast<const float4*>(x + (size_t)gr * DD + (c << 2));
      else        v = *reinterpret_cast<const float4*>(xout + (size_t)gr * DD + ((c - 32) << 2));
      unsigned short* dst = &A_lds[r][c << 2];
      dst[0] = f2b(v.x); dst[1] = f2b(v.y); dst[2] = f2b(v.z); dst[3] = f2b(v.w);
    }
    __syncthreads();

    f32x4 acc[4][2];
#pragma unroll
    for (int mf = 0; mf < 4; ++mf)
#pragma unroll
      for (int nf = 0; nf < 2; ++nf)
        acc[mf][nf] = (f32x4){0.f, 0.f, 0.f, 0.f};

#pragma unroll
    for (int kb = 0; kb < 8; ++kb) {
      bf16x8 a[4];
#pragma unroll
      for (int mf = 0; mf < 4; ++mf)
        a[mf] = *reinterpret_cast<const bf16x8*>(&A_lds[mf * 16 + lm][kb * 32 + lg * 8]);
#pragma unroll
      for (int mf = 0; mf < 4; ++mf)
#pragma unroll
        for (int nf = 0; nf < 2; ++nf)
          acc[mf][nf] = __builtin_amdgcn_mfma_f32_16x16x32_bf16(a[mf], w1f[kb][nf], acc[mf][nf], 0, 0, 0);
    }

#pragma unroll
    for (int mf = 0; mf < 4; ++mf)
#pragma unroll
      for (int nf = 0; nf < 2; ++nf)
#pragma unroll
        for (int rg = 0; rg < 4; ++rg) {
          const int m = mf * 16 + lg * 4 + rg;
          const int n = wv * 32 + nf * 16 + lm;
          float v = acc[mf][nf][rg] + b1[nf];
          h_lds[m][n] = f2b(v > 0.f ? v : 0.f);
        }
    __syncthreads();

    f32x4 acc2[4][2];
#pragma unroll
    for (int mf = 0; mf < 4; ++mf)
#pragma unroll
      for (int nf = 0; nf < 2; ++nf)
        acc2[mf][nf] = (f32x4){0.f, 0.f, 0.f, 0.f};

#pragma unroll
    for (int kb = 0; kb < 4; ++kb) {
      bf16x8 a[4];
#pragma unroll
      for (int mf = 0; mf < 4; ++mf)
        a[mf] = *reinterpret_cast<const bf16x8*>(&h_lds[mf * 16 + lm][kb * 32 + lg * 8]);
#pragma unroll
      for (int mf = 0; mf < 4; ++mf)
#pragma unroll
        for (int nf = 0; nf < 2; ++nf)
          acc2[mf][nf] = __builtin_amdgcn_mfma_f32_16x16x32_bf16(a[mf], w2f[kb][nf], acc2[mf][nf], 0, 0, 0);
    }

#pragma unroll
    for (int mf = 0; mf < 4; ++mf)
#pragma unroll
      for (int rg = 0; rg < 4; ++rg) {
        const int gm = nbase + mf * 16 + lg * 4 + rg;
        if (gm < N) {
#pragma unroll
          for (int nf = 0; nf < 2; ++nf) {
            const int n = wv * 32 + nf * 16 + lm;
            xout[(size_t)gm * DD + n] = acc2[mf][nf][rg] + b2[nf];
          }
        }
      }
  }
}

extern "C" void kernel_launch(void* const* d_in, const int* in_sizes, int n_in,
                              void* d_out, int out_size, void* d_ws, size_t ws_size,
                              hipStream_t stream) {
  const float* x   = (const float*)d_in[0];
  const int*   ei  = (const int*)d_in[1];
  const float* ea  = (const float*)d_in[2];
  const float* We1 = (const float*)d_in[3];
  const float* be1 = (const float*)d_in[4];
  const float* We2 = (const float*)d_in[5];
  const float* be2 = (const float*)d_in[6];
  const float* Wn1 = (const float*)d_in[7];
  const float* bn1 = (const float*)d_in[8];
  const float* Wn2 = (const float*)d_in[9];
  const float* bn2 = (const float*)d_in[10];

  const int N = in_sizes[0] / DD;   // 50000
  const int E = in_sizes[2] / DD;   // 600000

  float* out   = (float*)d_out;
  float* xout  = out;                    // x_out; early: PQ bf16 scratch
  float* e_out = out + (size_t)N * DD;   // e output

  unsigned short* pq = (unsigned short*)xout;  // [N][256] bf16, dead after edge kernel

  int* cnt  = (int*)d_ws;                // N
  int* off  = cnt + N;                   // N+1
  int* cur  = off + N + 1;               // N
  int* perm = cur + N;                   // E
  int* bsum = perm + E;                  // <=64

  const int SCAN_B = (N + 1023) / 1024;  // 49

  hipMemsetAsync(cnt, 0, (size_t)N * sizeof(int), stream);

  pq_kernel<<<(N + 63) / 64, 256, 0, stream>>>(x, We1, pq, N);

  count_kernel<<<(E + 255) / 256, 256, 0, stream>>>(ei, cnt, E);
  scan_a<<<SCAN_B, 256, 0, stream>>>(cnt, off, bsum, N);
  scan_b<<<1, 64, 0, stream>>>(bsum, SCAN_B);
  scan_c<<<SCAN_B, 256, 0, stream>>>(off, cur, bsum, N, E);
  fill_kernel<<<(E + 255) / 256, 256, 0, stream>>>(ei, cur, perm, E);

  edge_mlp_kernel<<<2048, 256, 0, stream>>>(pq, ei, ea, We1, be1, We2, be2, e_out, E);

  agg_kernel<<<(N + 3) / 4, 256, 0, stream>>>(e_out, off, perm, xout, N);

  const int node_tiles = (N + 63) / 64;
  node_mlp_kernel<<<node_tiles, 256, 0, stream>>>(x, Wn1, bn1, Wn2, bn2, xout, N);
}

// Round 11
// 383.867 us; speedup vs baseline: 1.6999x; 1.1022x over previous
//
#include <hip/hip_runtime.h>
#include <hip/hip_bf16.h>

#define DD 128

typedef short bf16x8 __attribute__((ext_vector_type(8)));
typedef float f32x4 __attribute__((ext_vector_type(4)));

__device__ __forceinline__ unsigned short f2b(float f) {
  unsigned int u = __float_as_uint(f);
  u = u + 0x7FFFu + ((u >> 16) & 1u);
  return (unsigned short)(u >> 16);
}

// async global->LDS 16B: per-lane global src, wave-uniform LDS dest (+lane*16)
#define GLDS16(gp, lp) __builtin_amdgcn_global_load_lds( \
    (const __attribute__((address_space(1))) unsigned int*)(const void*)(gp), \
    (__attribute__((address_space(3))) unsigned int*)(void*)(lp), 16, 0, 0)

// ---------------- x f32 -> bf16 ----------------
__global__ __launch_bounds__(256) void cvt_x_kernel(const float* __restrict__ x,
                                                    unsigned short* __restrict__ xb, int n4) {
  const int i = blockIdx.x * 256 + threadIdx.x;
  if (i < n4) {
    const float4 v = reinterpret_cast<const float4*>(x)[i];
    ushort4 o;
    o.x = f2b(v.x); o.y = f2b(v.y); o.z = f2b(v.z); o.w = f2b(v.w);
    reinterpret_cast<ushort4*>(xb)[i] = o;
  }
}

// ---------------- per-node in-degree ----------------
__global__ void count_kernel(const int* __restrict__ ei, int* __restrict__ cnt, int E) {
  int i = blockIdx.x * blockDim.x + threadIdx.x;
  if (i < E) atomicAdd(&cnt[ei[E + i]], 1);
}

// ---------------- prefix scan (3 kernels) ----------------
__global__ __launch_bounds__(256) void scan_a(const int* __restrict__ cnt,
                                              int* __restrict__ off,
                                              int* __restrict__ bsum, int N) {
  __shared__ int wsum[4];
  const int t = threadIdx.x;
  const int i0 = blockIdx.x * 1024 + t * 4;
  int4 v = {0, 0, 0, 0};
  if (i0 + 3 < N) v = *reinterpret_cast<const int4*>(cnt + i0);
  else {
    if (i0 < N)     v.x = cnt[i0];
    if (i0 + 1 < N) v.y = cnt[i0 + 1];
    if (i0 + 2 < N) v.z = cnt[i0 + 2];
    if (i0 + 3 < N) v.w = cnt[i0 + 3];
  }
  const int s1 = v.x, s2 = s1 + v.y, s3 = s2 + v.z, tot = s3 + v.w;
  const int lane = t & 63, wv = t >> 6;
  int sc = tot;
#pragma unroll
  for (int d = 1; d < 64; d <<= 1) {
    int u = __shfl_up(sc, d);
    if (lane >= d) sc += u;
  }
  if (lane == 63) wsum[wv] = sc;
  __syncthreads();
  int wpre = 0;
  for (int w = 0; w < wv; ++w) wpre += wsum[w];
  const int excl = wpre + sc - tot;
  if (i0 < N)     off[i0]     = excl;
  if (i0 + 1 < N) off[i0 + 1] = excl + s1;
  if (i0 + 2 < N) off[i0 + 2] = excl + s2;
  if (i0 + 3 < N) off[i0 + 3] = excl + s3;
  if (t == 255) bsum[blockIdx.x] = wpre + sc;
}

__global__ void scan_b(int* __restrict__ bsum, int B) {
  const int t = threadIdx.x;
  const int v0 = (t < B) ? bsum[t] : 0;
  int v = v0;
#pragma unroll
  for (int d = 1; d < 64; d <<= 1) {
    int u = __shfl_up(v, d);
    if (t >= d) v += u;
  }
  if (t < B) bsum[t] = v - v0;
}

__global__ __launch_bounds__(256) void scan_c(int* __restrict__ off, int* __restrict__ cur,
                                              const int* __restrict__ bsum, int N, int E) {
  const int t = threadIdx.x;
  const int add = bsum[blockIdx.x];
  const int i0 = blockIdx.x * 1024 + t * 4;
#pragma unroll
  for (int k = 0; k < 4; ++k) {
    const int i = i0 + k;
    if (i < N) {
      const int o = off[i] + add;
      off[i] = o;
      cur[i] = o;
    }
  }
  if (blockIdx.x == 0 && t == 0) off[N] = E;
}

__global__ void fill_kernel(const int* __restrict__ ei, int* __restrict__ cur,
                            int* __restrict__ perm, int E) {
  int i = blockIdx.x * blockDim.x + threadIdx.x;
  if (i < E) {
    const int d = ei[E + i];
    const int pos = atomicAdd(&cur[d], 1);
    perm[pos] = i;
  }
}

// ---------------- edge MLP: async-gather staging + MFMA (r3 exact) ----------------
// E is a multiple of 64 (600000 = 9375*64) — no tail handling.
__global__ __launch_bounds__(256, 2) void edge_mlp_kernel(
    const unsigned short* __restrict__ xb,   // [N][128] bf16
    const int* __restrict__ ei,              // [2][E]
    const float* __restrict__ ea,            // [E][128] f32
    const float* __restrict__ We1,
    const float* __restrict__ be1,
    const float* __restrict__ We2,
    const float* __restrict__ be2,
    float* __restrict__ e_out,               // [E][128] f32
    int E)
{
  // x blocks are staged by global_load_lds (linear dest, pre-swizzled source):
  // LDS[r][chunk j] holds global chunk (j ^ (r&7)); reads apply the same XOR.
  __shared__ __align__(16) unsigned short xs_lds[64][128];
  __shared__ __align__(16) unsigned short xd_lds[64][128];
  __shared__ __align__(16) unsigned short ea_lds[64][128];
  __shared__ __align__(16) unsigned short h_lds[64][136];
  __shared__ int srcs[64], dsts[64];

  const int tid  = threadIdx.x;
  const int wv   = tid >> 6;
  const int lane = tid & 63;
  const int lg   = lane >> 4;
  const int lm   = lane & 15;

  // ---- weight fragments in registers ----
  bf16x8 w1f[12][2];
  bf16x8 w2f[4][2];
  float b1[2], b2[2];
#pragma unroll
  for (int nf = 0; nf < 2; ++nf) {
    const int n = wv * 32 + nf * 16 + lm;
    b1[nf] = be1[n];
    b2[nf] = be2[n];
#pragma unroll
    for (int kb = 0; kb < 12; ++kb) {
      bf16x8 f;
#pragma unroll
      for (int j = 0; j < 8; ++j)
        f[j] = (short)f2b(We1[(kb * 32 + lg * 8 + j) * DD + n]);
      w1f[kb][nf] = f;
    }
#pragma unroll
    for (int kb = 0; kb < 4; ++kb) {
      bf16x8 f;
#pragma unroll
      for (int j = 0; j < 8; ++j)
        f[j] = (short)f2b(We2[(kb * 32 + lg * 8 + j) * DD + n]);
      w2f[kb][nf] = f;
    }
  }

  const int ntiles = E >> 6;
  for (int tile = blockIdx.x; tile < ntiles; tile += gridDim.x) {
    const int ebase = tile << 6;
    __syncthreads();  // previous tile's LDS readers done

    // ---- preload this tile's 128 indices ----
    if (tid < 64)       srcs[tid]      = ei[ebase + tid];
    else if (tid < 128) dsts[tid - 64] = ei[E + ebase + tid - 64];
    __syncthreads();

    // ---- async x gathers: each wave stages 16 rows of xs and xd ----
    {
#pragma unroll
      for (int wl = 0; wl < 4; ++wl) {
        const int r0 = wv * 16 + wl * 4;
        const int r  = r0 + (lane >> 4);
        const int ch = (lane & 15) ^ (r & 7);
        GLDS16(xb + (size_t)srcs[r] * DD + ch * 8, &xs_lds[r0][0]);
        GLDS16(xb + (size_t)dsts[r] * DD + ch * 8, &xd_lds[r0][0]);
      }
    }

    // ---- ea: coalesced f32 loads -> bf16 -> swizzled b128 LDS writes ----
    {
      float4 va[4], vb[4];
#pragma unroll
      for (int it = 0; it < 4; ++it) {
        const int q = tid + it * 256;
        const int r = q >> 4;
        const int c = q & 15;
        const float* p = ea + (size_t)(ebase + r) * DD + c * 8;
        va[it] = *reinterpret_cast<const float4*>(p);
        vb[it] = *reinterpret_cast<const float4*>(p + 4);
      }
#pragma unroll
      for (int it = 0; it < 4; ++it) {
        const int q = tid + it * 256;
        const int r = q >> 4;
        const int c = q & 15;
        bf16x8 o;
        o[0] = (short)f2b(va[it].x); o[1] = (short)f2b(va[it].y);
        o[2] = (short)f2b(va[it].z); o[3] = (short)f2b(va[it].w);
        o[4] = (short)f2b(vb[it].x); o[5] = (short)f2b(vb[it].y);
        o[6] = (short)f2b(vb[it].z); o[7] = (short)f2b(vb[it].w);
        *reinterpret_cast<bf16x8*>(&ea_lds[r][(c ^ (r & 7)) * 8]) = o;
      }
    }
    __syncthreads();  // drains vmcnt (incl. global_load_lds) + lgkm

    // ---- layer 1: h = relu(A @ We1 + be1), K = 384 ----
    f32x4 acc[4][2];
#pragma unroll
    for (int mf = 0; mf < 4; ++mf)
#pragma unroll
      for (int nf = 0; nf < 2; ++nf)
        acc[mf][nf] = (f32x4){0.f, 0.f, 0.f, 0.f};

#pragma unroll
    for (int kb = 0; kb < 12; ++kb) {
      const unsigned short (*blk)[128] = (kb < 4) ? xs_lds : (kb < 8) ? xd_lds : ea_lds;
      const int kl = kb & 3;
      bf16x8 a[4];
#pragma unroll
      for (int mf = 0; mf < 4; ++mf) {
        const int r = mf * 16 + lm;
        a[mf] = *reinterpret_cast<const bf16x8*>(&blk[r][((kl * 4 + lg) ^ (r & 7)) * 8]);
      }
#pragma unroll
      for (int mf = 0; mf < 4; ++mf)
#pragma unroll
        for (int nf = 0; nf < 2; ++nf)
          acc[mf][nf] = __builtin_amdgcn_mfma_f32_16x16x32_bf16(a[mf], w1f[kb][nf], acc[mf][nf], 0, 0, 0);
    }

#pragma unroll
    for (int mf = 0; mf < 4; ++mf)
#pragma unroll
      for (int nf = 0; nf < 2; ++nf)
#pragma unroll
        for (int rg = 0; rg < 4; ++rg) {
          const int m = mf * 16 + lg * 4 + rg;
          const int n = wv * 32 + nf * 16 + lm;
          float v = acc[mf][nf][rg] + b1[nf];
          h_lds[m][n] = f2b(v > 0.f ? v : 0.f);
        }
    __syncthreads();

    // ---- layer 2: e = h @ We2 + be2 ----
    f32x4 acc2[4][2];
#pragma unroll
    for (int mf = 0; mf < 4; ++mf)
#pragma unroll
      for (int nf = 0; nf < 2; ++nf)
        acc2[mf][nf] = (f32x4){0.f, 0.f, 0.f, 0.f};

#pragma unroll
    for (int kb = 0; kb < 4; ++kb) {
      bf16x8 a[4];
#pragma unroll
      for (int mf = 0; mf < 4; ++mf)
        a[mf] = *reinterpret_cast<const bf16x8*>(&h_lds[mf * 16 + lm][kb * 32 + lg * 8]);
#pragma unroll
      for (int mf = 0; mf < 4; ++mf)
#pragma unroll
        for (int nf = 0; nf < 2; ++nf)
          acc2[mf][nf] = __builtin_amdgcn_mfma_f32_16x16x32_bf16(a[mf], w2f[kb][nf], acc2[mf][nf], 0, 0, 0);
    }

    // ---- epilogue: write e ----
#pragma unroll
    for (int mf = 0; mf < 4; ++mf)
#pragma unroll
      for (int rg = 0; rg < 4; ++rg) {
        const int gm = ebase + mf * 16 + lg * 4 + rg;
#pragma unroll
        for (int nf = 0; nf < 2; ++nf) {
          const int n = wv * 32 + nf * 16 + lm;
          e_out[(size_t)gm * DD + n] = acc2[mf][nf][rg] + b2[nf];
        }
      }
  }
}

// ---------------- CSR scatter-mean: wave per node, 8-deep batched gathers ----
__global__ __launch_bounds__(256) void agg_kernel(const float* __restrict__ e_out,
                                                  const int* __restrict__ off,
                                                  const int* __restrict__ perm,
                                                  float* __restrict__ agg, int N) {
  const int wv   = threadIdx.x >> 6;
  const int lane = threadIdx.x & 63;
  const int nid  = blockIdx.x * 4 + wv;
  if (nid >= N) return;
  const int o0 = off[nid], o1 = off[nid + 1];
  float sx = 0.f, sy = 0.f;
  int j = o0;
  for (; j + 8 <= o1; j += 8) {
    int r[8];
#pragma unroll
    for (int k = 0; k < 8; ++k) r[k] = perm[j + k];
    float2 v[8];
#pragma unroll
    for (int k = 0; k < 8; ++k)
      v[k] = *reinterpret_cast<const float2*>(e_out + (size_t)r[k] * DD + (lane << 1));
#pragma unroll
    for (int k = 0; k < 8; ++k) { sx += v[k].x; sy += v[k].y; }
  }
  if (j + 4 <= o1) {
    int r[4];
#pragma unroll
    for (int k = 0; k < 4; ++k) r[k] = perm[j + k];
    float2 v[4];
#pragma unroll
    for (int k = 0; k < 4; ++k)
      v[k] = *reinterpret_cast<const float2*>(e_out + (size_t)r[k] * DD + (lane << 1));
#pragma unroll
    for (int k = 0; k < 4; ++k) { sx += v[k].x; sy += v[k].y; }
    j += 4;
  }
  for (; j < o1; ++j) {
    const int r = perm[j];
    const float2 v = *reinterpret_cast<const float2*>(e_out + (size_t)r * DD + (lane << 1));
    sx += v.x; sy += v.y;
  }
  const int deg = o1 - o0;
  const float inv = deg > 0 ? 1.f / (float)deg : 0.f;
  float2 o;
  o.x = sx * inv;
  o.y = sy * inv;
  *reinterpret_cast<float2*>(agg + (size_t)nid * DD + (lane << 1)) = o;
}

// ---------------- node MLP (r3 exact) ----------------
__global__ __launch_bounds__(256, 2) void node_mlp_kernel(
    const float* __restrict__ x,
    const float* __restrict__ Wn1,
    const float* __restrict__ bn1,
    const float* __restrict__ Wn2,
    const float* __restrict__ bn2,
    float* __restrict__ xout,        // in: agg mean, out: x_out
    int N)
{
  __shared__ __align__(16) unsigned short A_lds[64][264];
  __shared__ __align__(16) unsigned short h_lds[64][136];

  const int tid  = threadIdx.x;
  const int wv   = tid >> 6;
  const int lane = tid & 63;
  const int lg   = lane >> 4;
  const int lm   = lane & 15;

  bf16x8 w1f[8][2];
  bf16x8 w2f[4][2];
  float b1[2], b2[2];
#pragma unroll
  for (int nf = 0; nf < 2; ++nf) {
    const int n = wv * 32 + nf * 16 + lm;
    b1[nf] = bn1[n];
    b2[nf] = bn2[n];
#pragma unroll
    for (int kb = 0; kb < 8; ++kb) {
      bf16x8 f;
#pragma unroll
      for (int j = 0; j < 8; ++j)
        f[j] = (short)f2b(Wn1[(kb * 32 + lg * 8 + j) * DD + n]);
      w1f[kb][nf] = f;
    }
#pragma unroll
    for (int kb = 0; kb < 4; ++kb) {
      bf16x8 f;
#pragma unroll
      for (int j = 0; j < 8; ++j)
        f[j] = (short)f2b(Wn2[(kb * 32 + lg * 8 + j) * DD + n]);
      w2f[kb][nf] = f;
    }
  }

  const int ntiles = (N + 63) >> 6;
  for (int tile = blockIdx.x; tile < ntiles; tile += gridDim.x) {
    const int nbase = tile << 6;
    __syncthreads();

#pragma unroll
    for (int it = 0; it < 16; ++it) {
      const int q = tid + it * 256;
      const int r = q >> 6;
      const int c = q & 63;
      int gr = nbase + r;
      if (gr >= N) gr = N - 1;
      float4 v;
      if (c < 32) v = *reinterpret_cast<const float4*>(x + (size_t)gr * DD + (c << 2));
      else        v = *reinterpret_cast<const float4*>(xout + (size_t)gr * DD + ((c - 32) << 2));
      unsigned short* dst = &A_lds[r][c << 2];
      dst[0] = f2b(v.x); dst[1] = f2b(v.y); dst[2] = f2b(v.z); dst[3] = f2b(v.w);
    }
    __syncthreads();

    f32x4 acc[4][2];
#pragma unroll
    for (int mf = 0; mf < 4; ++mf)
#pragma unroll
      for (int nf = 0; nf < 2; ++nf)
        acc[mf][nf] = (f32x4){0.f, 0.f, 0.f, 0.f};

#pragma unroll
    for (int kb = 0; kb < 8; ++kb) {
      bf16x8 a[4];
#pragma unroll
      for (int mf = 0; mf < 4; ++mf)
        a[mf] = *reinterpret_cast<const bf16x8*>(&A_lds[mf * 16 + lm][kb * 32 + lg * 8]);
#pragma unroll
      for (int mf = 0; mf < 4; ++mf)
#pragma unroll
        for (int nf = 0; nf < 2; ++nf)
          acc[mf][nf] = __builtin_amdgcn_mfma_f32_16x16x32_bf16(a[mf], w1f[kb][nf], acc[mf][nf], 0, 0, 0);
    }

#pragma unroll
    for (int mf = 0; mf < 4; ++mf)
#pragma unroll
      for (int nf = 0; nf < 2; ++nf)
#pragma unroll
        for (int rg = 0; rg < 4; ++rg) {
          const int m = mf * 16 + lg * 4 + rg;
          const int n = wv * 32 + nf * 16 + lm;
          float v = acc[mf][nf][rg] + b1[nf];
          h_lds[m][n] = f2b(v > 0.f ? v : 0.f);
        }
    __syncthreads();

    f32x4 acc2[4][2];
#pragma unroll
    for (int mf = 0; mf < 4; ++mf)
#pragma unroll
      for (int nf = 0; nf < 2; ++nf)
        acc2[mf][nf] = (f32x4){0.f, 0.f, 0.f, 0.f};

#pragma unroll
    for (int kb = 0; kb < 4; ++kb) {
      bf16x8 a[4];
#pragma unroll
      for (int mf = 0; mf < 4; ++mf)
        a[mf] = *reinterpret_cast<const bf16x8*>(&h_lds[mf * 16 + lm][kb * 32 + lg * 8]);
#pragma unroll
      for (int mf = 0; mf < 4; ++mf)
#pragma unroll
        for (int nf = 0; nf < 2; ++nf)
          acc2[mf][nf] = __builtin_amdgcn_mfma_f32_16x16x32_bf16(a[mf], w2f[kb][nf], acc2[mf][nf], 0, 0, 0);
    }

#pragma unroll
    for (int mf = 0; mf < 4; ++mf)
#pragma unroll
      for (int rg = 0; rg < 4; ++rg) {
        const int gm = nbase + mf * 16 + lg * 4 + rg;
        if (gm < N) {
#pragma unroll
          for (int nf = 0; nf < 2; ++nf) {
            const int n = wv * 32 + nf * 16 + lm;
            xout[(size_t)gm * DD + n] = acc2[mf][nf][rg] + b2[nf];
          }
        }
      }
  }
}

extern "C" void kernel_launch(void* const* d_in, const int* in_sizes, int n_in,
                              void* d_out, int out_size, void* d_ws, size_t ws_size,
                              hipStream_t stream) {
  const float* x   = (const float*)d_in[0];
  const int*   ei  = (const int*)d_in[1];
  const float* ea  = (const float*)d_in[2];
  const float* We1 = (const float*)d_in[3];
  const float* be1 = (const float*)d_in[4];
  const float* We2 = (const float*)d_in[5];
  const float* be2 = (const float*)d_in[6];
  const float* Wn1 = (const float*)d_in[7];
  const float* bn1 = (const float*)d_in[8];
  const float* Wn2 = (const float*)d_in[9];
  const float* bn2 = (const float*)d_in[10];

  const int N = in_sizes[0] / DD;   // 50000
  const int E = in_sizes[2] / DD;   // 600000

  float* out   = (float*)d_out;
  float* xout  = out;                    // x_out; early: x_bf16 scratch, then agg mean
  float* e_out = out + (size_t)N * DD;   // e output

  unsigned short* xb = (unsigned short*)xout;  // x as bf16 (dead after edge kernel)

  int* cnt  = (int*)d_ws;                // N
  int* off  = cnt + N;                   // N+1
  int* cur  = off + N + 1;               // N
  int* perm = cur + N;                   // E
  int* bsum = perm + E;                  // <=64

  const int SCAN_B = (N + 1023) / 1024;  // 49

  hipMemsetAsync(cnt, 0, (size_t)N * sizeof(int), stream);

  cvt_x_kernel<<<(N * DD / 4 + 255) / 256, 256, 0, stream>>>(x, xb, N * DD / 4);

  count_kernel<<<(E + 255) / 256, 256, 0, stream>>>(ei, cnt, E);
  scan_a<<<SCAN_B, 256, 0, stream>>>(cnt, off, bsum, N);
  scan_b<<<1, 64, 0, stream>>>(bsum, SCAN_B);
  scan_c<<<SCAN_B, 256, 0, stream>>>(off, cur, bsum, N, E);
  fill_kernel<<<(E + 255) / 256, 256, 0, stream>>>(ei, cur, perm, E);

  edge_mlp_kernel<<<2048, 256, 0, stream>>>(xb, ei, ea, We1, be1, We2, be2, e_out, E);

  agg_kernel<<<(N + 3) / 4, 256, 0, stream>>>(e_out, off, perm, xout, N);

  const int node_tiles = (N + 63) / 64;
  node_mlp_kernel<<<node_tiles, 256, 0, stream>>>(x, Wn1, bn1, Wn2, bn2, xout, N);
}

// Round 12
// 369.125 us; speedup vs baseline: 1.7678x; 1.0399x over previous
//
#include <hip/hip_runtime.h>
#include <hip/hip_bf16.h>

#define DD 128

typedef short bf16x8 __attribute__((ext_vector_type(8)));
typedef float f32x4 __attribute__((ext_vector_type(4)));
typedef float f32x2v __attribute__((ext_vector_type(2)));

__device__ __forceinline__ unsigned short f2b(float f) {
  unsigned int u = __float_as_uint(f);
  u = u + 0x7FFFu + ((u >> 16) & 1u);
  return (unsigned short)(u >> 16);
}

// async global->LDS 16B: per-lane global src, wave-uniform LDS dest (+lane*16)
#define GLDS16(gp, lp) __builtin_amdgcn_global_load_lds( \
    (const __attribute__((address_space(1))) unsigned int*)(const void*)(gp), \
    (__attribute__((address_space(3))) unsigned int*)(void*)(lp), 16, 0, 0)

// ---------------- x f32 -> bf16 ----------------
__global__ __launch_bounds__(256) void cvt_x_kernel(const float* __restrict__ x,
                                                    unsigned short* __restrict__ xb, int n4) {
  const int i = blockIdx.x * 256 + threadIdx.x;
  if (i < n4) {
    const float4 v = reinterpret_cast<const float4*>(x)[i];
    ushort4 o;
    o.x = f2b(v.x); o.y = f2b(v.y); o.z = f2b(v.z); o.w = f2b(v.w);
    reinterpret_cast<ushort4*>(xb)[i] = o;
  }
}

// ---------------- per-node in-degree ----------------
__global__ void count_kernel(const int* __restrict__ ei, int* __restrict__ cnt, int E) {
  int i = blockIdx.x * blockDim.x + threadIdx.x;
  if (i < E) atomicAdd(&cnt[ei[E + i]], 1);
}

// ---------------- prefix scan (3 kernels) ----------------
__global__ __launch_bounds__(256) void scan_a(const int* __restrict__ cnt,
                                              int* __restrict__ off,
                                              int* __restrict__ bsum, int N) {
  __shared__ int wsum[4];
  const int t = threadIdx.x;
  const int i0 = blockIdx.x * 1024 + t * 4;
  int4 v = {0, 0, 0, 0};
  if (i0 + 3 < N) v = *reinterpret_cast<const int4*>(cnt + i0);
  else {
    if (i0 < N)     v.x = cnt[i0];
    if (i0 + 1 < N) v.y = cnt[i0 + 1];
    if (i0 + 2 < N) v.z = cnt[i0 + 2];
    if (i0 + 3 < N) v.w = cnt[i0 + 3];
  }
  const int s1 = v.x, s2 = s1 + v.y, s3 = s2 + v.z, tot = s3 + v.w;
  const int lane = t & 63, wv = t >> 6;
  int sc = tot;
#pragma unroll
  for (int d = 1; d < 64; d <<= 1) {
    int u = __shfl_up(sc, d);
    if (lane >= d) sc += u;
  }
  if (lane == 63) wsum[wv] = sc;
  __syncthreads();
  int wpre = 0;
  for (int w = 0; w < wv; ++w) wpre += wsum[w];
  const int excl = wpre + sc - tot;
  if (i0 < N)     off[i0]     = excl;
  if (i0 + 1 < N) off[i0 + 1] = excl + s1;
  if (i0 + 2 < N) off[i0 + 2] = excl + s2;
  if (i0 + 3 < N) off[i0 + 3] = excl + s3;
  if (t == 255) bsum[blockIdx.x] = wpre + sc;
}

__global__ void scan_b(int* __restrict__ bsum, int B) {
  const int t = threadIdx.x;
  const int v0 = (t < B) ? bsum[t] : 0;
  int v = v0;
#pragma unroll
  for (int d = 1; d < 64; d <<= 1) {
    int u = __shfl_up(v, d);
    if (t >= d) v += u;
  }
  if (t < B) bsum[t] = v - v0;
}

__global__ __launch_bounds__(256) void scan_c(int* __restrict__ off, int* __restrict__ cur,
                                              const int* __restrict__ bsum, int N, int E) {
  const int t = threadIdx.x;
  const int add = bsum[blockIdx.x];
  const int i0 = blockIdx.x * 1024 + t * 4;
#pragma unroll
  for (int k = 0; k < 4; ++k) {
    const int i = i0 + k;
    if (i < N) {
      const int o = off[i] + add;
      off[i] = o;
      cur[i] = o;
    }
  }
  if (blockIdx.x == 0 && t == 0) off[N] = E;
}

__global__ void fill_kernel(const int* __restrict__ ei, int* __restrict__ cur,
                            int* __restrict__ perm, int E) {
  int i = blockIdx.x * blockDim.x + threadIdx.x;
  if (i < E) {
    const int d = ei[E + i];
    const int pos = atomicAdd(&cur[d], 1);
    perm[pos] = i;
  }
}

// ---------------- edge MLP: r3/r11 body + nontemporal stream hints ----------------
// E is a multiple of 64 (600000 = 9375*64) — no tail handling.
__global__ __launch_bounds__(256, 2) void edge_mlp_kernel(
    const unsigned short* __restrict__ xb,   // [N][128] bf16
    const int* __restrict__ ei,              // [2][E]
    const float* __restrict__ ea,            // [E][128] f32
    const float* __restrict__ We1,
    const float* __restrict__ be1,
    const float* __restrict__ We2,
    const float* __restrict__ be2,
    float* __restrict__ e_out,               // [E][128] f32
    int E)
{
  // x blocks are staged by global_load_lds (linear dest, pre-swizzled source):
  // LDS[r][chunk j] holds global chunk (j ^ (r&7)); reads apply the same XOR.
  __shared__ __align__(16) unsigned short xs_lds[64][128];
  __shared__ __align__(16) unsigned short xd_lds[64][128];
  __shared__ __align__(16) unsigned short ea_lds[64][128];
  __shared__ __align__(16) unsigned short h_lds[64][136];
  __shared__ int srcs[64], dsts[64];

  const int tid  = threadIdx.x;
  const int wv   = tid >> 6;
  const int lane = tid & 63;
  const int lg   = lane >> 4;
  const int lm   = lane & 15;

  // ---- weight fragments in registers ----
  bf16x8 w1f[12][2];
  bf16x8 w2f[4][2];
  float b1[2], b2[2];
#pragma unroll
  for (int nf = 0; nf < 2; ++nf) {
    const int n = wv * 32 + nf * 16 + lm;
    b1[nf] = be1[n];
    b2[nf] = be2[n];
#pragma unroll
    for (int kb = 0; kb < 12; ++kb) {
      bf16x8 f;
#pragma unroll
      for (int j = 0; j < 8; ++j)
        f[j] = (short)f2b(We1[(kb * 32 + lg * 8 + j) * DD + n]);
      w1f[kb][nf] = f;
    }
#pragma unroll
    for (int kb = 0; kb < 4; ++kb) {
      bf16x8 f;
#pragma unroll
      for (int j = 0; j < 8; ++j)
        f[j] = (short)f2b(We2[(kb * 32 + lg * 8 + j) * DD + n]);
      w2f[kb][nf] = f;
    }
  }

  const int ntiles = E >> 6;
  for (int tile = blockIdx.x; tile < ntiles; tile += gridDim.x) {
    const int ebase = tile << 6;
    __syncthreads();  // previous tile's LDS readers done

    // ---- preload this tile's 128 indices ----
    if (tid < 64)       srcs[tid]      = ei[ebase + tid];
    else if (tid < 128) dsts[tid - 64] = ei[E + ebase + tid - 64];
    __syncthreads();

    // ---- async x gathers: each wave stages 16 rows of xs and xd ----
    {
#pragma unroll
      for (int wl = 0; wl < 4; ++wl) {
        const int r0 = wv * 16 + wl * 4;
        const int r  = r0 + (lane >> 4);
        const int ch = (lane & 15) ^ (r & 7);
        GLDS16(xb + (size_t)srcs[r] * DD + ch * 8, &xs_lds[r0][0]);
        GLDS16(xb + (size_t)dsts[r] * DD + ch * 8, &xd_lds[r0][0]);
      }
    }

    // ---- ea: nontemporal f32 stream -> bf16 -> swizzled b128 LDS writes ----
    {
      f32x4 va[4], vb[4];
#pragma unroll
      for (int it = 0; it < 4; ++it) {
        const int q = tid + it * 256;
        const int r = q >> 4;
        const int c = q & 15;
        const float* p = ea + (size_t)(ebase + r) * DD + c * 8;
        va[it] = __builtin_nontemporal_load(reinterpret_cast<const f32x4*>(p));
        vb[it] = __builtin_nontemporal_load(reinterpret_cast<const f32x4*>(p + 4));
      }
#pragma unroll
      for (int it = 0; it < 4; ++it) {
        const int q = tid + it * 256;
        const int r = q >> 4;
        const int c = q & 15;
        bf16x8 o;
        o[0] = (short)f2b(va[it][0]); o[1] = (short)f2b(va[it][1]);
        o[2] = (short)f2b(va[it][2]); o[3] = (short)f2b(va[it][3]);
        o[4] = (short)f2b(vb[it][0]); o[5] = (short)f2b(vb[it][1]);
        o[6] = (short)f2b(vb[it][2]); o[7] = (short)f2b(vb[it][3]);
        *reinterpret_cast<bf16x8*>(&ea_lds[r][(c ^ (r & 7)) * 8]) = o;
      }
    }
    __syncthreads();  // drains vmcnt (incl. global_load_lds) + lgkm

    // ---- layer 1: h = relu(A @ We1 + be1), K = 384 ----
    f32x4 acc[4][2];
#pragma unroll
    for (int mf = 0; mf < 4; ++mf)
#pragma unroll
      for (int nf = 0; nf < 2; ++nf)
        acc[mf][nf] = (f32x4){0.f, 0.f, 0.f, 0.f};

#pragma unroll
    for (int kb = 0; kb < 12; ++kb) {
      const unsigned short (*blk)[128] = (kb < 4) ? xs_lds : (kb < 8) ? xd_lds : ea_lds;
      const int kl = kb & 3;
      bf16x8 a[4];
#pragma unroll
      for (int mf = 0; mf < 4; ++mf) {
        const int r = mf * 16 + lm;
        a[mf] = *reinterpret_cast<const bf16x8*>(&blk[r][((kl * 4 + lg) ^ (r & 7)) * 8]);
      }
#pragma unroll
      for (int mf = 0; mf < 4; ++mf)
#pragma unroll
        for (int nf = 0; nf < 2; ++nf)
          acc[mf][nf] = __builtin_amdgcn_mfma_f32_16x16x32_bf16(a[mf], w1f[kb][nf], acc[mf][nf], 0, 0, 0);
    }

#pragma unroll
    for (int mf = 0; mf < 4; ++mf)
#pragma unroll
      for (int nf = 0; nf < 2; ++nf)
#pragma unroll
        for (int rg = 0; rg < 4; ++rg) {
          const int m = mf * 16 + lg * 4 + rg;
          const int n = wv * 32 + nf * 16 + lm;
          float v = acc[mf][nf][rg] + b1[nf];
          h_lds[m][n] = f2b(v > 0.f ? v : 0.f);
        }
    __syncthreads();

    // ---- layer 2: e = h @ We2 + be2 ----
    f32x4 acc2[4][2];
#pragma unroll
    for (int mf = 0; mf < 4; ++mf)
#pragma unroll
      for (int nf = 0; nf < 2; ++nf)
        acc2[mf][nf] = (f32x4){0.f, 0.f, 0.f, 0.f};

#pragma unroll
    for (int kb = 0; kb < 4; ++kb) {
      bf16x8 a[4];
#pragma unroll
      for (int mf = 0; mf < 4; ++mf)
        a[mf] = *reinterpret_cast<const bf16x8*>(&h_lds[mf * 16 + lm][kb * 32 + lg * 8]);
#pragma unroll
      for (int mf = 0; mf < 4; ++mf)
#pragma unroll
        for (int nf = 0; nf < 2; ++nf)
          acc2[mf][nf] = __builtin_amdgcn_mfma_f32_16x16x32_bf16(a[mf], w2f[kb][nf], acc2[mf][nf], 0, 0, 0);
    }

    // ---- epilogue: nontemporal e stores (write-once stream) ----
#pragma unroll
    for (int mf = 0; mf < 4; ++mf)
#pragma unroll
      for (int rg = 0; rg < 4; ++rg) {
        const int gm = ebase + mf * 16 + lg * 4 + rg;
#pragma unroll
        for (int nf = 0; nf < 2; ++nf) {
          const int n = wv * 32 + nf * 16 + lm;
          __builtin_nontemporal_store(acc2[mf][nf][rg] + b2[nf],
                                      &e_out[(size_t)gm * DD + n]);
        }
      }
  }
}

// ---------------- CSR scatter-mean: wave per node, 8-deep batched gathers ----
__global__ __launch_bounds__(256) void agg_kernel(const float* __restrict__ e_out,
                                                  const int* __restrict__ off,
                                                  const int* __restrict__ perm,
                                                  float* __restrict__ agg, int N) {
  const int wv   = threadIdx.x >> 6;
  const int lane = threadIdx.x & 63;
  const int nid  = blockIdx.x * 4 + wv;
  if (nid >= N) return;
  const int o0 = off[nid], o1 = off[nid + 1];
  float sx = 0.f, sy = 0.f;
  int j = o0;
  for (; j + 8 <= o1; j += 8) {
    int r[8];
#pragma unroll
    for (int k = 0; k < 8; ++k) r[k] = perm[j + k];
    f32x2v v[8];
#pragma unroll
    for (int k = 0; k < 8; ++k)
      v[k] = __builtin_nontemporal_load(
          reinterpret_cast<const f32x2v*>(e_out + (size_t)r[k] * DD + (lane << 1)));
#pragma unroll
    for (int k = 0; k < 8; ++k) { sx += v[k][0]; sy += v[k][1]; }
  }
  if (j + 4 <= o1) {
    int r[4];
#pragma unroll
    for (int k = 0; k < 4; ++k) r[k] = perm[j + k];
    f32x2v v[4];
#pragma unroll
    for (int k = 0; k < 4; ++k)
      v[k] = __builtin_nontemporal_load(
          reinterpret_cast<const f32x2v*>(e_out + (size_t)r[k] * DD + (lane << 1)));
#pragma unroll
    for (int k = 0; k < 4; ++k) { sx += v[k][0]; sy += v[k][1]; }
    j += 4;
  }
  for (; j < o1; ++j) {
    const int r = perm[j];
    const f32x2v v = __builtin_nontemporal_load(
        reinterpret_cast<const f32x2v*>(e_out + (size_t)r * DD + (lane << 1)));
    sx += v[0]; sy += v[1];
  }
  const int deg = o1 - o0;
  const float inv = deg > 0 ? 1.f / (float)deg : 0.f;
  float2 o;
  o.x = sx * inv;
  o.y = sy * inv;
  *reinterpret_cast<float2*>(agg + (size_t)nid * DD + (lane << 1)) = o;
}

// ---------------- node MLP (r11 exact) ----------------
__global__ __launch_bounds__(256, 2) void node_mlp_kernel(
    const float* __restrict__ x,
    const float* __restrict__ Wn1,
    const float* __restrict__ bn1,
    const float* __restrict__ Wn2,
    const float* __restrict__ bn2,
    float* __restrict__ xout,        // in: agg mean, out: x_out
    int N)
{
  __shared__ __align__(16) unsigned short A_lds[64][264];
  __shared__ __align__(16) unsigned short h_lds[64][136];

  const int tid  = threadIdx.x;
  const int wv   = tid >> 6;
  const int lane = tid & 63;
  const int lg   = lane >> 4;
  const int lm   = lane & 15;

  bf16x8 w1f[8][2];
  bf16x8 w2f[4][2];
  float b1[2], b2[2];
#pragma unroll
  for (int nf = 0; nf < 2; ++nf) {
    const int n = wv * 32 + nf * 16 + lm;
    b1[nf] = bn1[n];
    b2[nf] = bn2[n];
#pragma unroll
    for (int kb = 0; kb < 8; ++kb) {
      bf16x8 f;
#pragma unroll
      for (int j = 0; j < 8; ++j)
        f[j] = (short)f2b(Wn1[(kb * 32 + lg * 8 + j) * DD + n]);
      w1f[kb][nf] = f;
    }
#pragma unroll
    for (int kb = 0; kb < 4; ++kb) {
      bf16x8 f;
#pragma unroll
      for (int j = 0; j < 8; ++j)
        f[j] = (short)f2b(Wn2[(kb * 32 + lg * 8 + j) * DD + n]);
      w2f[kb][nf] = f;
    }
  }

  const int ntiles = (N + 63) >> 6;
  for (int tile = blockIdx.x; tile < ntiles; tile += gridDim.x) {
    const int nbase = tile << 6;
    __syncthreads();

#pragma unroll
    for (int it = 0; it < 16; ++it) {
      const int q = tid + it * 256;
      const int r = q >> 6;
      const int c = q & 63;
      int gr = nbase + r;
      if (gr >= N) gr = N - 1;
      float4 v;
      if (c < 32) v = *reinterpret_cast<const float4*>(x + (size_t)gr * DD + (c << 2));
      else        v = *reinterpret_cast<const float4*>(xout + (size_t)gr * DD + ((c - 32) << 2));
      unsigned short* dst = &A_lds[r][c << 2];
      dst[0] = f2b(v.x); dst[1] = f2b(v.y); dst[2] = f2b(v.z); dst[3] = f2b(v.w);
    }
    __syncthreads();

    f32x4 acc[4][2];
#pragma unroll
    for (int mf = 0; mf < 4; ++mf)
#pragma unroll
      for (int nf = 0; nf < 2; ++nf)
        acc[mf][nf] = (f32x4){0.f, 0.f, 0.f, 0.f};

#pragma unroll
    for (int kb = 0; kb < 8; ++kb) {
      bf16x8 a[4];
#pragma unroll
      for (int mf = 0; mf < 4; ++mf)
        a[mf] = *reinterpret_cast<const bf16x8*>(&A_lds[mf * 16 + lm][kb * 32 + lg * 8]);
#pragma unroll
      for (int mf = 0; mf < 4; ++mf)
#pragma unroll
        for (int nf = 0; nf < 2; ++nf)
          acc[mf][nf] = __builtin_amdgcn_mfma_f32_16x16x32_bf16(a[mf], w1f[kb][nf], acc[mf][nf], 0, 0, 0);
    }

#pragma unroll
    for (int mf = 0; mf < 4; ++mf)
#pragma unroll
      for (int nf = 0; nf < 2; ++nf)
#pragma unroll
        for (int rg = 0; rg < 4; ++rg) {
          const int m = mf * 16 + lg * 4 + rg;
          const int n = wv * 32 + nf * 16 + lm;
          float v = acc[mf][nf][rg] + b1[nf];
          h_lds[m][n] = f2b(v > 0.f ? v : 0.f);
        }
    __syncthreads();

    f32x4 acc2[4][2];
#pragma unroll
    for (int mf = 0; mf < 4; ++mf)
#pragma unroll
      for (int nf = 0; nf < 2; ++nf)
        acc2[mf][nf] = (f32x4){0.f, 0.f, 0.f, 0.f};

#pragma unroll
    for (int kb = 0; kb < 4; ++kb) {
      bf16x8 a[4];
#pragma unroll
      for (int mf = 0; mf < 4; ++mf)
        a[mf] = *reinterpret_cast<const bf16x8*>(&h_lds[mf * 16 + lm][kb * 32 + lg * 8]);
#pragma unroll
      for (int mf = 0; mf < 4; ++mf)
#pragma unroll
        for (int nf = 0; nf < 2; ++nf)
          acc2[mf][nf] = __builtin_amdgcn_mfma_f32_16x16x32_bf16(a[mf], w2f[kb][nf], acc2[mf][nf], 0, 0, 0);
    }

#pragma unroll
    for (int mf = 0; mf < 4; ++mf)
#pragma unroll
      for (int rg = 0; rg < 4; ++rg) {
        const int gm = nbase + mf * 16 + lg * 4 + rg;
        if (gm < N) {
#pragma unroll
          for (int nf = 0; nf < 2; ++nf) {
            const int n = wv * 32 + nf * 16 + lm;
            xout[(size_t)gm * DD + n] = acc2[mf][nf][rg] + b2[nf];
          }
        }
      }
  }
}

extern "C" void kernel_launch(void* const* d_in, const int* in_sizes, int n_in,
                              void* d_out, int out_size, void* d_ws, size_t ws_size,
                              hipStream_t stream) {
  const float* x   = (const float*)d_in[0];
  const int*   ei  = (const int*)d_in[1];
  const float* ea  = (const float*)d_in[2];
  const float* We1 = (const float*)d_in[3];
  const float* be1 = (const float*)d_in[4];
  const float* We2 = (const float*)d_in[5];
  const float* be2 = (const float*)d_in[6];
  const float* Wn1 = (const float*)d_in[7];
  const float* bn1 = (const float*)d_in[8];
  const float* Wn2 = (const float*)d_in[9];
  const float* bn2 = (const float*)d_in[10];

  const int N = in_sizes[0] / DD;   // 50000
  const int E = in_sizes[2] / DD;   // 600000

  float* out   = (float*)d_out;
  float* xout  = out;                    // x_out; early: x_bf16 scratch, then agg mean
  float* e_out = out + (size_t)N * DD;   // e output

  unsigned short* xb = (unsigned short*)xout;  // x as bf16 (dead after edge kernel)

  int* cnt  = (int*)d_ws;                // N
  int* off  = cnt + N;                   // N+1
  int* cur  = off + N + 1;               // N
  int* perm = cur + N;                   // E
  int* bsum = perm + E;                  // <=64

  const int SCAN_B = (N + 1023) / 1024;  // 49

  hipMemsetAsync(cnt, 0, (size_t)N * sizeof(int), stream);

  cvt_x_kernel<<<(N * DD / 4 + 255) / 256, 256, 0, stream>>>(x, xb, N * DD / 4);

  count_kernel<<<(E + 255) / 256, 256, 0, stream>>>(ei, cnt, E);
  scan_a<<<SCAN_B, 256, 0, stream>>>(cnt, off, bsum, N);
  scan_b<<<1, 64, 0, stream>>>(bsum, SCAN_B);
  scan_c<<<SCAN_B, 256, 0, stream>>>(off, cur, bsum, N, E);
  fill_kernel<<<(E + 255) / 256, 256, 0, stream>>>(ei, cur, perm, E);

  edge_mlp_kernel<<<2048, 256, 0, stream>>>(xb, ei, ea, We1, be1, We2, be2, e_out, E);

  agg_kernel<<<(N + 3) / 4, 256, 0, stream>>>(e_out, off, perm, xout, N);

  const int node_tiles = (N + 63) / 64;
  node_mlp_kernel<<<node_tiles, 256, 0, stream>>>(x, Wn1, bn1, Wn2, bn2, xout, N);
}